// Round 4
// baseline (2125.469 us; speedup 1.0000x reference)
//
#include <hip/hip_runtime.h>

#define M_DIM 8192
#define N_DIM 11008
#define K_DIM 4096
#define GROUPS 32     // K / 128
#define LDSK 72       // slow kernel pad

typedef short s16x8 __attribute__((ext_vector_type(8)));
typedef float f32x4 __attribute__((ext_vector_type(4)));
typedef unsigned short u16;
typedef unsigned int u32;

union f32u { float f; unsigned u; };
union h16u { u16 u; _Float16 h; };

__device__ __forceinline__ u16 f2bf(float f) {
  f32u v; v.f = f;
  unsigned r = v.u + 0x7FFFu + ((v.u >> 16) & 1u);  // RNE
  return (u16)(r >> 16);
}
__device__ __forceinline__ float bf2f(u16 b) {
  f32u v; v.u = ((unsigned)b) << 16; return v.f;
}
__device__ __forceinline__ float h2f(u16 b) {
  h16u v; v.u = b; return (float)v.h;
}
__device__ __forceinline__ float magicf(u32 bits) {
  f32u v; v.u = bits; return v.f;
}
__device__ __forceinline__ u32 cvt_pk_bf16(float lo, float hi) {
  u32 r;
  asm("v_cvt_pk_bf16_f32 %0, %1, %2" : "=v"(r) : "v"(lo), "v"(hi));
  return r;
}

// ---------------------------------------------------------------------------
// Probe (R2/R3 empirics: harness promotes fp16 -> f32, so expect mode 0).
// ---------------------------------------------------------------------------
__global__ void probe_mode_kernel(const void* __restrict__ scales,
                                  int* __restrict__ mode_out) {
  __shared__ int cnt[3];
  int t = threadIdx.x;
  if (t < 3) cnt[t] = 0;
  __syncthreads();
  float f0 = ((const float*)scales)[t];
  u16  hu  = ((const u16*)scales)[t];
  float f1 = h2f(hu);
  float f2 = bf2f(hu);
  if (f0 > 0.0004f && f0 < 0.065f) atomicAdd(&cnt[0], 1);
  if (f1 > 0.0004f && f1 < 0.065f) atomicAdd(&cnt[1], 1);
  if (f2 > 0.0004f && f2 < 0.065f) atomicAdd(&cnt[2], 1);
  __syncthreads();
  if (t == 0) {
    int m;
    if      (cnt[1] >= 240) m = 1;  // raw fp16 bits
    else if (cnt[2] >= 240) m = 2;  // raw bf16 bits
    else                    m = 0;  // f32
    mode_out[0] = m;
  }
}

// ---------------------------------------------------------------------------
// Pre-pass: x f32 -> bf16 (RNE) into ws. 33.5M elems, 8 per thread per sweep.
// ---------------------------------------------------------------------------
__global__ __launch_bounds__(256) void convert_x_kernel(
    const float* __restrict__ xf, u16* __restrict__ xb,
    const int* __restrict__ modep) {
  if (modep && modep[0] != 0) return;
  const long total8 = (long)M_DIM * K_DIM / 8;           // 4,194,304
  long idx = blockIdx.x * 256 + threadIdx.x;
  const long stride = (long)gridDim.x * 256;
  for (; idx < total8; idx += stride) {
    const float4* p = (const float4*)(xf + idx * 8);
    float4 a = p[0], b = p[1];
    union { u32 u[4]; s16x8 v; } r;
    r.u[0] = cvt_pk_bf16(a.x, a.y);
    r.u[1] = cvt_pk_bf16(a.z, a.w);
    r.u[2] = cvt_pk_bf16(b.x, b.y);
    r.u[3] = cvt_pk_bf16(b.z, b.w);
    *(s16x8*)(xb + idx * 8) = r.v;
  }
}

// ---------------------------------------------------------------------------
// In-register dequant: dword's LOW BYTE = 2 nibbles (low->even k, high->odd).
// 0x43000000|(nib<<16) = 128+nib exactly; (v-136)*s via fma c=-136*s; pack bf16.
// ---------------------------------------------------------------------------
__device__ __forceinline__ s16x8 dequant8_bf16(int4 p, float s, float c) {
  union { u32 u[4]; s16x8 v; } r;
  const int d[4] = {p.x, p.y, p.z, p.w};
  #pragma unroll
  for (int e = 0; e < 4; ++e) {
    u32 ve = 0x43000000u | (((u32)d[e] << 16) & 0x000F0000u);
    u32 vo = 0x43000000u | (((u32)d[e] << 12) & 0x000F0000u);
    float fe = fmaf(magicf(ve), s, c);
    float fo = fmaf(magicf(vo), s, c);
    r.u[e] = cvt_pk_bf16(fe, fo);
  }
  return r.v;
}

// ---------------------------------------------------------------------------
// FAST PATH (mode==0): A = pre-converted bf16 from ws via global_load_lds
// (dbuf + XOR swizzle); B = in-register dequant; scales f32 direct.
// BM=128, BN=256, BK=64; 4 waves 1x4 in n; acc 8x4 of 16x16x32 bf16 MFMA.
// ---------------------------------------------------------------------------
__global__ __launch_bounds__(256, 2) void q4gemm_fast_kernel(
    const u16* __restrict__ xb,      // bf16 (converted)
    const int* __restrict__ packed,  // 1 byte per int32, 2 nibbles
    const float* __restrict__ scf,   // f32 scales
    float* __restrict__ out,
    const int* __restrict__ modep)
{
  if (modep && modep[0] != 0) return;

  __shared__ u16 As[2][128 * 64];    // 32 KiB total

  const int tid  = threadIdx.x;
  const int lane = tid & 63;
  const int wv   = tid >> 6;

  // XCD-aware bijective swizzle: grid 2752 = 8 * 344; bm-minor so same-XCD
  // neighbors share the 2MB packed n-panel in L2.
  int bid = blockIdx.x;
  int f   = (bid & 7) * 344 + (bid >> 3);
  int bn  = f / 64;
  int bm  = f - bn * 64;
  const int n0 = bn * 256;
  const int m0 = bm * 128;

  // ---- A staging: LDS[row][slot] = G[row][slot ^ (row&7)] (16B chunks)
  const int srow  = lane >> 3;             // 0..7 within 8-row stripe
  const int sperm = (lane & 7) ^ srow;
  const u16* abase[4];
  #pragma unroll
  for (int q = 0; q < 4; ++q) {
    int row = (wv * 4 + q) * 8 + srow;
    abase[q] = xb + (long)(m0 + row) * K_DIM + sperm * 8;
  }

  // ---- B addresses: fragment (j,kkc) = 4 consecutive int32 of col's row
  const int ln15 = lane & 15;
  const int lk   = lane >> 4;              // k-chunk 0..3
  int pbase[4], sbase[4];
  #pragma unroll
  for (int j = 0; j < 4; ++j) {
    int col  = n0 + wv * 64 + j * 16 + ln15;
    pbase[j] = col * (K_DIM / 2) + lk * 4; // dword index (fits 32-bit)
    sbase[j] = col * GROUPS;
  }

  f32x4 acc[8][4];
  #pragma unroll
  for (int i = 0; i < 8; ++i)
    #pragma unroll
    for (int j = 0; j < 4; ++j)
      acc[i][j] = f32x4{0.f, 0.f, 0.f, 0.f};

  // ---- prologue: stage tile 0 into buf 0; prefetch scales g=0
  #pragma unroll
  for (int q = 0; q < 4; ++q)
    __builtin_amdgcn_global_load_lds(
        (const __attribute__((address_space(1))) void*)abase[q],
        (__attribute__((address_space(3))) void*)&As[0][(wv * 4 + q) * 512],
        16, 0, 0);

  float snext[4];
  #pragma unroll
  for (int j = 0; j < 4; ++j) snext[j] = scf[sbase[j]];

  __syncthreads();

  for (int g = 0; g < GROUPS; ++g) {
    float s[4], c[4];
    #pragma unroll
    for (int j = 0; j < 4; ++j) {
      s[j] = snext[j];
      c[j] = -136.0f * s[j];
    }
    if (g < GROUPS - 1) {
      #pragma unroll
      for (int j = 0; j < 4; ++j) snext[j] = scf[sbase[j] + g + 1];
    }

    #pragma unroll
    for (int half = 0; half < 2; ++half) {
      const int t   = g * 2 + half;
      const int cur = t & 1;

      // B raw: 8 x int4 (this K-tile's fragments), issued early
      int4 raw[4][2];
      #pragma unroll
      for (int j = 0; j < 4; ++j) {
        const int4* pp = (const int4*)(packed + pbase[j] + t * 32);
        raw[j][0] = pp[0];
        raw[j][1] = pp[4];                 // +16 dwords (k+32)
      }

      // stage A(t+1) into the other buffer — in flight through the MFMAs
      if (t < 63) {
        #pragma unroll
        for (int q = 0; q < 4; ++q)
          __builtin_amdgcn_global_load_lds(
              (const __attribute__((address_space(1))) void*)(abase[q] + (t + 1) * 64),
              (__attribute__((address_space(3))) void*)&As[cur ^ 1][(wv * 4 + q) * 512],
              16, 0, 0);
      }

      #pragma unroll
      for (int kkc = 0; kkc < 2; ++kkc) {
        s16x8 af[8];
        #pragma unroll
        for (int i = 0; i < 8; ++i) {
          int row  = i * 16 + ln15;
          int slot = (kkc * 4 + lk) ^ (row & 7);   // XOR-swizzled read
          af[i] = *(const s16x8*)&As[cur][row * 64 + slot * 8];
        }
        #pragma unroll
        for (int j = 0; j < 4; ++j) {
          s16x8 bf = dequant8_bf16(raw[j][kkc], s[j], c[j]);
          #pragma unroll
          for (int i = 0; i < 8; ++i)
            acc[i][j] = __builtin_amdgcn_mfma_f32_16x16x32_bf16(af[i], bf, acc[i][j], 0, 0, 0);
        }
      }
      __syncthreads();
    }
  }

  // ---- epilogue: C/D layout col=lane&15, row=(lane>>4)*4+reg
  #pragma unroll
  for (int i = 0; i < 8; ++i) {
    int r0 = m0 + i * 16 + (lane >> 4) * 4;
    #pragma unroll
    for (int j = 0; j < 4; ++j) {
      int cc = n0 + wv * 64 + j * 16 + ln15;
      #pragma unroll
      for (int r = 0; r < 4; ++r)
        out[(long)(r0 + r) * N_DIM + cc] = acc[i][j][r];
    }
  }
}

// ---------------------------------------------------------------------------
// SLOW FALLBACK (all modes; skip0 set when the fast path covers mode 0).
// ---------------------------------------------------------------------------
__global__ __launch_bounds__(256) void q4gemm_slow_kernel(
    const void* __restrict__ xraw,
    const int*  __restrict__ packed,
    const void* __restrict__ scraw,
    float* __restrict__ out,
    const int* __restrict__ modep,
    int skip0)
{
  const int mode = modep ? modep[0] : 0;
  if (skip0 && mode == 0) return;

  __shared__ u16 Asl[128 * LDSK];
  __shared__ u16 Bsl[128 * LDSK];

  const int tid  = threadIdx.x;
  const int lane = tid & 63;
  const int wv   = tid >> 6;
  const int wm   = (wv >> 1) * 64;
  const int wn   = (wv & 1) * 64;
  const int n0   = blockIdx.x * 128;
  const int m0   = blockIdx.y * 128;

  f32x4 acc[4][4];
  #pragma unroll
  for (int i = 0; i < 4; ++i)
    #pragma unroll
    for (int j = 0; j < 4; ++j)
      acc[i][j] = f32x4{0.f, 0.f, 0.f, 0.f};

  const int lrow16 = lane & 15;
  const int lk8    = (lane >> 4) * 8;

  for (int k0 = 0; k0 < K_DIM; k0 += 64) {
    if (mode == 0) {
      const float* xf = (const float*)xraw;
      #pragma unroll
      for (int it = 0; it < 4; ++it) {
        int s = tid + it * 256;
        int row = s >> 3, c8 = (s & 7) * 8;
        const float4* p = (const float4*)(xf + (long)(m0 + row) * K_DIM + k0 + c8);
        float4 v0 = p[0], v1 = p[1];
        u16 tmp[8] = { f2bf(v0.x), f2bf(v0.y), f2bf(v0.z), f2bf(v0.w),
                       f2bf(v1.x), f2bf(v1.y), f2bf(v1.z), f2bf(v1.w) };
        *(s16x8*)&Asl[row * LDSK + c8] = *(const s16x8*)tmp;
      }
    } else if (mode == 1) {
      const u16* xhh = (const u16*)xraw;
      #pragma unroll
      for (int it = 0; it < 4; ++it) {
        int s = tid + it * 256;
        int row = s >> 3, c8 = (s & 7) * 8;
        s16x8 v = *(const s16x8*)(xhh + (long)(m0 + row) * K_DIM + k0 + c8);
        u16 tmp[8];
        #pragma unroll
        for (int j = 0; j < 8; ++j) tmp[j] = f2bf(h2f((u16)v[j]));
        *(s16x8*)&Asl[row * LDSK + c8] = *(const s16x8*)tmp;
      }
    } else {
      const u16* xhh = (const u16*)xraw;
      #pragma unroll
      for (int it = 0; it < 4; ++it) {
        int s = tid + it * 256;
        int row = s >> 3, c8 = (s & 7) * 8;
        s16x8 v = *(const s16x8*)(xhh + (long)(m0 + row) * K_DIM + k0 + c8);
        *(s16x8*)&Asl[row * LDSK + c8] = v;   // bf16 passthrough
      }
    }

    {
      int row  = tid >> 1;
      int half = tid & 1;
      int srw  = n0 + row;
      int g    = k0 >> 7;
      float scale;
      if      (mode == 0) scale = ((const float*)scraw)[(long)srw * GROUPS + g];
      else if (mode == 1) scale = h2f(((const u16*)scraw)[(long)srw * GROUPS + g]);
      else                scale = bf2f(((const u16*)scraw)[(long)srw * GROUPS + g]);

      const int4* pp = (const int4*)(packed + (long)srw * (K_DIM / 2) + (k0 >> 1) + half * 16);
      #pragma unroll
      for (int j = 0; j < 4; ++j) {
        int4 pv = pp[j];
        int vals[4] = {pv.x, pv.y, pv.z, pv.w};
        u16 w[8];
        #pragma unroll
        for (int e = 0; e < 4; ++e) {
          int b = vals[e] & 255;
          w[e * 2]     = f2bf(scale * (float)((b & 15) - 8));
          w[e * 2 + 1] = f2bf(scale * (float)(((b >> 4) & 15) - 8));
        }
        int i0 = half * 16 + j * 4;
        *(s16x8*)&Bsl[row * LDSK + i0 * 2] = *(const s16x8*)w;
      }
    }
    __syncthreads();

    #pragma unroll
    for (int kk = 0; kk < 64; kk += 32) {
      s16x8 af[4], bfr[4];
      int klane = kk + lk8;
      #pragma unroll
      for (int i = 0; i < 4; ++i)
        af[i] = *(const s16x8*)&Asl[(wm + i * 16 + lrow16) * LDSK + klane];
      #pragma unroll
      for (int i = 0; i < 4; ++i)
        bfr[i] = *(const s16x8*)&Bsl[(wn + i * 16 + lrow16) * LDSK + klane];
      #pragma unroll
      for (int i = 0; i < 4; ++i)
        #pragma unroll
        for (int j = 0; j < 4; ++j)
          acc[i][j] = __builtin_amdgcn_mfma_f32_16x16x32_bf16(af[i], bfr[j], acc[i][j], 0, 0, 0);
    }
    __syncthreads();
  }

  #pragma unroll
  for (int i = 0; i < 4; ++i) {
    int rbase = m0 + wm + i * 16 + ((lane >> 4) * 4);
    #pragma unroll
    for (int j = 0; j < 4; ++j) {
      int c = n0 + wn + j * 16 + (lane & 15);
      #pragma unroll
      for (int r = 0; r < 4; ++r)
        out[(long)(rbase + r) * N_DIM + c] = acc[i][j][r];
    }
  }
}

extern "C" void kernel_launch(void* const* d_in, const int* in_sizes, int n_in,
                              void* d_out, int out_size, void* d_ws, size_t ws_size,
                              hipStream_t stream) {
  const void* x      = d_in[0];
  const int*  packed = (const int*)d_in[1];
  const void* scales = d_in[2];
  float* out = (float*)d_out;

  const size_t XB_BYTES = (size_t)M_DIM * K_DIM * 2;   // 67.1 MB bf16
  const size_t NEED = 256 + XB_BYTES;

  int* mode_flag = nullptr;
  if (ws_size >= 4) {
    mode_flag = (int*)d_ws;
    probe_mode_kernel<<<dim3(1), dim3(256), 0, stream>>>(scales, mode_flag);
  }

  int fast_ok = (ws_size >= NEED) ? 1 : 0;

  if (fast_ok) {
    u16* xb = (u16*)((char*)d_ws + 256);
    convert_x_kernel<<<dim3(2048), dim3(256), 0, stream>>>(
        (const float*)x, xb, mode_flag);
    q4gemm_fast_kernel<<<dim3(2752), dim3(256), 0, stream>>>(
        xb, packed, (const float*)scales, out, mode_flag);
  }

  // fallback: modes 1/2 always; mode 0 only when fast path unavailable
  q4gemm_slow_kernel<<<dim3(N_DIM / 128, M_DIM / 128), dim3(256), 0, stream>>>(
      x, packed, scales, out, mode_flag, fast_ok);
}

// Round 7
// 1493.969 us; speedup vs baseline: 1.4227x; 1.4227x over previous
//
#include <hip/hip_runtime.h>

#define M_DIM 8192
#define N_DIM 11008
#define K_DIM 4096
#define GROUPS 32     // K / 128
#define WQROW 512     // dwords per row of compact W = K/8
#define LDSK 72       // slow kernel pad

typedef short s16x8 __attribute__((ext_vector_type(8)));
typedef _Float16 f16x8 __attribute__((ext_vector_type(8)));
typedef _Float16 h2 __attribute__((ext_vector_type(2)));
typedef float f32x4 __attribute__((ext_vector_type(4)));
typedef unsigned short u16;
typedef unsigned int u32;

union f32u { float f; unsigned u; };
union h16u { u16 u; _Float16 h; };

__device__ __forceinline__ u16 f2bf(float f) {
  f32u v; v.f = f;
  unsigned r = v.u + 0x7FFFu + ((v.u >> 16) & 1u);  // RNE
  return (u16)(r >> 16);
}
__device__ __forceinline__ float bf2f(u16 b) {
  f32u v; v.u = ((unsigned)b) << 16; return v.f;
}
__device__ __forceinline__ float h2f(u16 b) {
  h16u v; v.u = b; return (float)v.h;
}

// ---------------------------------------------------------------------------
// Probe (R3/R4 empirics: harness promotes fp16 -> f32 => mode 0).
// ---------------------------------------------------------------------------
__global__ void probe_mode_kernel(const void* __restrict__ scales,
                                  int* __restrict__ mode_out) {
  __shared__ int cnt[3];
  int t = threadIdx.x;
  if (t < 3) cnt[t] = 0;
  __syncthreads();
  float f0 = ((const float*)scales)[t];
  u16  hu  = ((const u16*)scales)[t];
  float f1 = h2f(hu);
  float f2 = bf2f(hu);
  if (f0 > 0.0004f && f0 < 0.065f) atomicAdd(&cnt[0], 1);
  if (f1 > 0.0004f && f1 < 0.065f) atomicAdd(&cnt[1], 1);
  if (f2 > 0.0004f && f2 < 0.065f) atomicAdd(&cnt[2], 1);
  __syncthreads();
  if (t == 0) {
    int m;
    if      (cnt[1] >= 240) m = 1;
    else if (cnt[2] >= 240) m = 2;
    else                    m = 0;
    mode_out[0] = m;
  }
}

// ---------------------------------------------------------------------------
// Pre-pass 1: x f32 -> fp16, PERMUTED within each 8-chunk to the dequant's
// register order [x0,x4,x1,x5,x2,x6,x3,x7]. Exact (x was fp16 originally).
// ---------------------------------------------------------------------------
__global__ __launch_bounds__(256) void convert_x_kernel(
    const float* __restrict__ xf, u16* __restrict__ xh,
    const int* __restrict__ modep) {
  if (modep && modep[0] != 0) return;
  const int total8 = M_DIM * (K_DIM / 8);   // 4,194,304 chunks
  int idx = blockIdx.x * 256 + threadIdx.x;
  const int stride = gridDim.x * 256;
  for (; idx < total8; idx += stride) {
    const float4* p = (const float4*)(xf + (size_t)idx * 8);
    float4 a = p[0], b = p[1];
    union { _Float16 h[8]; s16x8 v; } r;
    r.h[0] = (_Float16)a.x; r.h[1] = (_Float16)b.x;   // (x0, x4)
    r.h[2] = (_Float16)a.y; r.h[3] = (_Float16)b.y;   // (x1, x5)
    r.h[4] = (_Float16)a.z; r.h[5] = (_Float16)b.z;   // (x2, x6)
    r.h[6] = (_Float16)a.w; r.h[7] = (_Float16)b.w;   // (x3, x7)
    *(s16x8*)(xh + (size_t)idx * 8) = r.v;
  }
}

// ---------------------------------------------------------------------------
// Pre-pass 2: compact W: 4 int32 (1 payload byte each) -> 1 dword of 8
// nibbles. R7 FIX: one dword covers 8 k-values, so each row has K/8 = 512
// dwords (was wrongly 256: only half of `packed` repacked AND wrong column
// stride in the GEMM). Flat mapping: wq[col*512 + d] <- bytes of
// packed[col*2048 + d*4 .. +3]; nibble n of wq-dword = k = d*8 + n.
// ---------------------------------------------------------------------------
__global__ __launch_bounds__(256) void repack_w_kernel(
    const int* __restrict__ packed, u32* __restrict__ wq) {
  const int total = N_DIM * WQROW;          // 5,636,096 dwords
  int idx = blockIdx.x * 256 + threadIdx.x;
  const int stride = gridDim.x * 256;
  for (; idx < total; idx += stride) {
    const int4 p = ((const int4*)packed)[idx];
    wq[idx] = (u32)(p.x & 255) | ((u32)(p.y & 255) << 8) |
              ((u32)(p.z & 255) << 16) | ((u32)p.w << 24);
  }
}

// ---------------------------------------------------------------------------
// Dequant 8 weights from one nibble-dword. Register fp16 order:
// (k0,k4),(k1,k5),(k2,k6),(k3,k7) — matched by the permuted x layout.
// (1024+nib) - 1032 = nib-8 exact in fp16; * s (exact fp16) -> ref-exact W.
// ---------------------------------------------------------------------------
__device__ __forceinline__ f16x8 dq8(u32 q, h2 s2) {
  const u32 M = 0x000F000Fu, G = 0x64006400u;
  const h2 bias = {(_Float16)(-1032.0f), (_Float16)(-1032.0f)};
  union { u32 u; h2 h; } a0, a1, a2, a3;
  a0.u = (q & M) | G;
  a1.u = ((q >> 4) & M) | G;
  a2.u = ((q >> 8) & M) | G;
  a3.u = ((q >> 12) & M) | G;
  a0.h = (a0.h + bias) * s2;
  a1.h = (a1.h + bias) * s2;
  a2.h = (a2.h + bias) * s2;
  a3.h = (a3.h + bias) * s2;
  union { u32 u[4]; f16x8 f; } r;
  r.u[0] = a0.u; r.u[1] = a1.u; r.u[2] = a2.u; r.u[3] = a3.u;
  return r.f;
}

// ---------------------------------------------------------------------------
// FAST PATH (mode 0): BM=256, BN=256, BK=64; 8 waves (2m x 4n), each 128x64
// (acc 8x4). A: fp16 from ws via global_load_lds (dbuf + XOR swizzle). B:
// one compact dword per fragment, in-register dequant. R7: wq stride 512.
// ---------------------------------------------------------------------------
__global__ __launch_bounds__(512, 2) void q4gemm_fast_kernel(
    const u16* __restrict__ xh,      // fp16, permuted 8-chunks
    const u32* __restrict__ wq,      // compact nibbles [N][512]
    const float* __restrict__ scf,   // f32 scales [N][32]
    float* __restrict__ out,
    const int* __restrict__ modep)
{
  if (modep && modep[0] != 0) return;

  __shared__ _Float16 As[2][256 * 64];   // 64 KiB

  const int tid  = threadIdx.x;
  const int lane = tid & 63;
  const int wv   = tid >> 6;             // 0..7
  const int wm   = (wv >> 2) * 128;      // 2 waves in m
  const int wn   = (wv & 3) * 64;        // 4 waves in n
  const int ln15 = lane & 15;
  const int lk   = lane >> 4;            // 0..3

  // XCD swizzle: 1376 = 8 * 172; per XCD bm-major (172 = 4 bm-groups x 43 bn)
  int bid = blockIdx.x;
  int f   = (bid & 7) * 172 + (bid >> 3);
  int bm  = f / 43;
  int bn  = f - bm * 43;
  const int m0 = bm * 256;
  const int n0 = bn * 256;

  // ---- A staging addresses: LDS[row][slot] = G[row][slot ^ (row&7)]
  const u16* abase[4];
  #pragma unroll
  for (int q = 0; q < 4; ++q) {
    int row = q * 64 + wv * 8 + (lane >> 3);
    abase[q] = xh + (size_t)(m0 + row) * K_DIM + (((lane & 7) ^ (lane >> 3)) * 8);
  }

#define STAGE(BUF, T) do { \
    _Pragma("unroll") \
    for (int q = 0; q < 4; ++q) \
      __builtin_amdgcn_global_load_lds( \
          (const __attribute__((address_space(1))) void*)(abase[q] + (T) * 64), \
          (__attribute__((address_space(3))) void*)(&As[BUF][q * 4096 + wv * 512]), \
          16, 0, 0); \
  } while (0)

  // ---- B/scale addresses (R7: row stride 512 dwords)
  int pcol[4], scol[4];
  #pragma unroll
  for (int j = 0; j < 4; ++j) {
    int col = n0 + wn + j * 16 + ln15;
    pcol[j] = col * WQROW + lk;          // dword index into wq
    scol[j] = col * GROUPS;
  }

  f32x4 acc[8][4];
  #pragma unroll
  for (int i = 0; i < 8; ++i)
    #pragma unroll
    for (int j = 0; j < 4; ++j)
      acc[i][j] = f32x4{0.f, 0.f, 0.f, 0.f};

  // ---- prologue
  STAGE(0, 0);
  u32 rA0[4], rA1[4], rB0[4], rB1[4];
  #pragma unroll
  for (int j = 0; j < 4; ++j) {
    rA0[j] = wq[pcol[j]];
    rA1[j] = wq[pcol[j] + 4];
  }
  float snextf[4];
  #pragma unroll
  for (int j = 0; j < 4; ++j) snextf[j] = scf[scol[j]];
  __syncthreads();

  for (int g = 0; g < GROUPS; ++g) {
    h2 s2[4];
    #pragma unroll
    for (int j = 0; j < 4; ++j) {
      _Float16 sh = (_Float16)snextf[j];
      s2[j] = h2{sh, sh};
    }
    if (g < GROUPS - 1) {
      #pragma unroll
      for (int j = 0; j < 4; ++j) snextf[j] = scf[scol[j] + g + 1];
    }

    // ================= phase A: t = 2g (As[0], rA) =================
    {
      const int t = 2 * g;
      STAGE(1, t + 1);                       // t+1 <= 63 always
      #pragma unroll
      for (int j = 0; j < 4; ++j) {          // prefetch B for tile t+1 (phase B)
        rB0[j] = wq[pcol[j] + (t + 1) * 8];
        rB1[j] = wq[pcol[j] + (t + 1) * 8 + 4];
      }
      #pragma unroll
      for (int kkc = 0; kkc < 2; ++kkc) {
        f16x8 bf0 = dq8(kkc ? rA1[0] : rA0[0], s2[0]);
        f16x8 bf1 = dq8(kkc ? rA1[1] : rA0[1], s2[1]);
        f16x8 bf2 = dq8(kkc ? rA1[2] : rA0[2], s2[2]);
        f16x8 bf3 = dq8(kkc ? rA1[3] : rA0[3], s2[3]);
        #pragma unroll
        for (int i = 0; i < 8; ++i) {
          const int row  = wm + i * 16 + ln15;
          const int slot = (kkc * 4 + lk) ^ (ln15 & 7);
          f16x8 af = *(const f16x8*)&As[0][row * 64 + slot * 8];
          acc[i][0] = __builtin_amdgcn_mfma_f32_16x16x32_f16(af, bf0, acc[i][0], 0, 0, 0);
          acc[i][1] = __builtin_amdgcn_mfma_f32_16x16x32_f16(af, bf1, acc[i][1], 0, 0, 0);
          acc[i][2] = __builtin_amdgcn_mfma_f32_16x16x32_f16(af, bf2, acc[i][2], 0, 0, 0);
          acc[i][3] = __builtin_amdgcn_mfma_f32_16x16x32_f16(af, bf3, acc[i][3], 0, 0, 0);
        }
      }
      __syncthreads();
    }

    // ================= phase B: t = 2g+1 (As[1], rB) =================
    {
      const int t = 2 * g + 1;
      if (t < 63) STAGE(0, t + 1);
      const int tn = (t + 1 <= 63) ? (t + 1) : 0;   // next phase A's tile
      #pragma unroll
      for (int j = 0; j < 4; ++j) {                 // prefetch B for tile t+1
        rA0[j] = wq[pcol[j] + tn * 8];
        rA1[j] = wq[pcol[j] + tn * 8 + 4];
      }
      #pragma unroll
      for (int kkc = 0; kkc < 2; ++kkc) {
        f16x8 bf0 = dq8(kkc ? rB1[0] : rB0[0], s2[0]);
        f16x8 bf1 = dq8(kkc ? rB1[1] : rB0[1], s2[1]);
        f16x8 bf2 = dq8(kkc ? rB1[2] : rB0[2], s2[2]);
        f16x8 bf3 = dq8(kkc ? rB1[3] : rB0[3], s2[3]);
        #pragma unroll
        for (int i = 0; i < 8; ++i) {
          const int row  = wm + i * 16 + ln15;
          const int slot = (kkc * 4 + lk) ^ (ln15 & 7);
          f16x8 af = *(const f16x8*)&As[1][row * 64 + slot * 8];
          acc[i][0] = __builtin_amdgcn_mfma_f32_16x16x32_f16(af, bf0, acc[i][0], 0, 0, 0);
          acc[i][1] = __builtin_amdgcn_mfma_f32_16x16x32_f16(af, bf1, acc[i][1], 0, 0, 0);
          acc[i][2] = __builtin_amdgcn_mfma_f32_16x16x32_f16(af, bf2, acc[i][2], 0, 0, 0);
          acc[i][3] = __builtin_amdgcn_mfma_f32_16x16x32_f16(af, bf3, acc[i][3], 0, 0, 0);
        }
      }
      __syncthreads();
    }
  }

  // ---- epilogue: C/D col=lane&15, row=(lane>>4)*4+reg
  #pragma unroll
  for (int i = 0; i < 8; ++i) {
    int r0 = m0 + wm + i * 16 + (lane >> 4) * 4;
    #pragma unroll
    for (int j = 0; j < 4; ++j) {
      int cc = n0 + wn + j * 16 + ln15;
      #pragma unroll
      for (int r = 0; r < 4; ++r)
        out[(size_t)(r0 + r) * N_DIM + cc] = acc[i][j][r];
    }
  }
#undef STAGE
}

// ---------------------------------------------------------------------------
// SLOW FALLBACK (any mode; skips mode 0 when fast path ran).
// ---------------------------------------------------------------------------
__global__ __launch_bounds__(256) void q4gemm_slow_kernel(
    const void* __restrict__ xraw,
    const int*  __restrict__ packed,
    const void* __restrict__ scraw,
    float* __restrict__ out,
    const int* __restrict__ modep,
    int skip0)
{
  const int mode = modep ? modep[0] : 0;
  if (skip0 && mode == 0) return;

  __shared__ u16 Asl[128 * LDSK];
  __shared__ u16 Bsl[128 * LDSK];

  const int tid  = threadIdx.x;
  const int lane = tid & 63;
  const int wv   = tid >> 6;
  const int wm   = (wv >> 1) * 64;
  const int wn   = (wv & 1) * 64;
  const int n0   = blockIdx.x * 128;
  const int m0   = blockIdx.y * 128;

  f32x4 acc[4][4];
  #pragma unroll
  for (int i = 0; i < 4; ++i)
    #pragma unroll
    for (int j = 0; j < 4; ++j)
      acc[i][j] = f32x4{0.f, 0.f, 0.f, 0.f};

  const int lrow16 = lane & 15;
  const int lk8    = (lane >> 4) * 8;

  for (int k0 = 0; k0 < K_DIM; k0 += 64) {
    if (mode == 0) {
      const float* xf = (const float*)xraw;
      #pragma unroll
      for (int it = 0; it < 4; ++it) {
        int s = tid + it * 256;
        int row = s >> 3, c8 = (s & 7) * 8;
        const float4* p = (const float4*)(xf + (size_t)(m0 + row) * K_DIM + k0 + c8);
        float4 v0 = p[0], v1 = p[1];
        u16 tmp[8] = { f2bf(v0.x), f2bf(v0.y), f2bf(v0.z), f2bf(v0.w),
                       f2bf(v1.x), f2bf(v1.y), f2bf(v1.z), f2bf(v1.w) };
        *(s16x8*)&Asl[row * LDSK + c8] = *(const s16x8*)tmp;
      }
    } else if (mode == 1) {
      const u16* xhh = (const u16*)xraw;
      #pragma unroll
      for (int it = 0; it < 4; ++it) {
        int s = tid + it * 256;
        int row = s >> 3, c8 = (s & 7) * 8;
        s16x8 v = *(const s16x8*)(xhh + (size_t)(m0 + row) * K_DIM + k0 + c8);
        u16 tmp[8];
        #pragma unroll
        for (int j = 0; j < 8; ++j) tmp[j] = f2bf(h2f((u16)v[j]));
        *(s16x8*)&Asl[row * LDSK + c8] = *(const s16x8*)tmp;
      }
    } else {
      const u16* xhh = (const u16*)xraw;
      #pragma unroll
      for (int it = 0; it < 4; ++it) {
        int s = tid + it * 256;
        int row = s >> 3, c8 = (s & 7) * 8;
        s16x8 v = *(const s16x8*)(xhh + (size_t)(m0 + row) * K_DIM + k0 + c8);
        *(s16x8*)&Asl[row * LDSK + c8] = v;
      }
    }

    {
      int row  = tid >> 1;
      int half = tid & 1;
      int srw  = n0 + row;
      int g    = k0 >> 7;
      float scale;
      if      (mode == 0) scale = ((const float*)scraw)[(size_t)srw * GROUPS + g];
      else if (mode == 1) scale = h2f(((const u16*)scraw)[(size_t)srw * GROUPS + g]);
      else                scale = bf2f(((const u16*)scraw)[(size_t)srw * GROUPS + g]);

      const int4* pp = (const int4*)(packed + (size_t)srw * (K_DIM / 2) + (k0 >> 1) + half * 16);
      #pragma unroll
      for (int j = 0; j < 4; ++j) {
        int4 pv = pp[j];
        int vals[4] = {pv.x, pv.y, pv.z, pv.w};
        u16 w[8];
        #pragma unroll
        for (int e = 0; e < 4; ++e) {
          int b = vals[e] & 255;
          w[e * 2]     = f2bf(scale * (float)((b & 15) - 8));
          w[e * 2 + 1] = f2bf(scale * (float)(((b >> 4) & 15) - 8));
        }
        int i0 = half * 16 + j * 4;
        *(s16x8*)&Bsl[row * LDSK + i0 * 2] = *(const s16x8*)w;
      }
    }
    __syncthreads();

    #pragma unroll
    for (int kk = 0; kk < 64; kk += 32) {
      s16x8 af[4], bfr[4];
      int klane = kk + lk8;
      #pragma unroll
      for (int i = 0; i < 4; ++i)
        af[i] = *(const s16x8*)&Asl[(wm + i * 16 + lrow16) * LDSK + klane];
      #pragma unroll
      for (int i = 0; i < 4; ++i)
        bfr[i] = *(const s16x8*)&Bsl[(wn + i * 16 + lrow16) * LDSK + klane];
      #pragma unroll
      for (int i = 0; i < 4; ++i)
        #pragma unroll
        for (int j = 0; j < 4; ++j)
          acc[i][j] = __builtin_amdgcn_mfma_f32_16x16x32_bf16(af[i], bfr[j], acc[i][j], 0, 0, 0);
    }
    __syncthreads();
  }

  #pragma unroll
  for (int i = 0; i < 4; ++i) {
    int rbase = m0 + wm + i * 16 + ((lane >> 4) * 4);
    #pragma unroll
    for (int j = 0; j < 4; ++j) {
      int c = n0 + wn + j * 16 + (lane & 15);
      #pragma unroll
      for (int r = 0; r < 4; ++r)
        out[(size_t)(rbase + r) * N_DIM + c] = acc[i][j][r];
    }
  }
}

extern "C" void kernel_launch(void* const* d_in, const int* in_sizes, int n_in,
                              void* d_out, int out_size, void* d_ws, size_t ws_size,
                              hipStream_t stream) {
  const void* x      = d_in[0];
  const int*  packed = (const int*)d_in[1];
  const void* scales = d_in[2];
  float* out = (float*)d_out;

  const size_t XB = (size_t)M_DIM * K_DIM * 2;        // 67,108,864 B
  const size_t WQ = (size_t)N_DIM * WQROW * 4;        // 22,544,384 B
  const size_t NEED = 256 + XB + WQ;

  int* mode_flag = nullptr;
  if (ws_size >= 4) {
    mode_flag = (int*)d_ws;
    probe_mode_kernel<<<dim3(1), dim3(256), 0, stream>>>(scales, mode_flag);
  }

  int fast_ok = (ws_size >= NEED && mode_flag) ? 1 : 0;

  if (fast_ok) {
    u16* xh = (u16*)((char*)d_ws + 256);
    u32* wq = (u32*)((char*)d_ws + 256 + XB);
    convert_x_kernel<<<dim3(2048), dim3(256), 0, stream>>>(
        (const float*)x, xh, mode_flag);
    repack_w_kernel<<<dim3(2048), dim3(256), 0, stream>>>(packed, wq);
    q4gemm_fast_kernel<<<dim3(1376), dim3(512), 0, stream>>>(
        xh, wq, (const float*)scales, out, mode_flag);
  }

  q4gemm_slow_kernel<<<dim3(N_DIM / 128, M_DIM / 128), dim3(256), 0, stream>>>(
      x, packed, scales, out, mode_flag, fast_ok);
}

// Round 8
// 1399.992 us; speedup vs baseline: 1.5182x; 1.0671x over previous
//
#include <hip/hip_runtime.h>

#define M_DIM 8192
#define N_DIM 11008
#define K_DIM 4096
#define GROUPS 32     // K / 128
#define WQROW 512     // dwords per row of compact W = K/8
#define LDSK 72       // slow kernel pad

typedef short s16x8 __attribute__((ext_vector_type(8)));
typedef _Float16 f16x8 __attribute__((ext_vector_type(8)));
typedef _Float16 h2 __attribute__((ext_vector_type(2)));
typedef float f32x4 __attribute__((ext_vector_type(4)));
typedef unsigned short u16;
typedef unsigned int u32;

union f32u { float f; unsigned u; };
union h16u { u16 u; _Float16 h; };

__device__ __forceinline__ u16 f2bf(float f) {
  f32u v; v.f = f;
  unsigned r = v.u + 0x7FFFu + ((v.u >> 16) & 1u);  // RNE
  return (u16)(r >> 16);
}
__device__ __forceinline__ float bf2f(u16 b) {
  f32u v; v.u = ((unsigned)b) << 16; return v.f;
}
__device__ __forceinline__ float h2f(u16 b) {
  h16u v; v.u = b; return (float)v.h;
}

// ---------------------------------------------------------------------------
// Probe (R3/R4 empirics: harness promotes fp16 -> f32 => mode 0).
// ---------------------------------------------------------------------------
__global__ void probe_mode_kernel(const void* __restrict__ scales,
                                  int* __restrict__ mode_out) {
  __shared__ int cnt[3];
  int t = threadIdx.x;
  if (t < 3) cnt[t] = 0;
  __syncthreads();
  float f0 = ((const float*)scales)[t];
  u16  hu  = ((const u16*)scales)[t];
  float f1 = h2f(hu);
  float f2 = bf2f(hu);
  if (f0 > 0.0004f && f0 < 0.065f) atomicAdd(&cnt[0], 1);
  if (f1 > 0.0004f && f1 < 0.065f) atomicAdd(&cnt[1], 1);
  if (f2 > 0.0004f && f2 < 0.065f) atomicAdd(&cnt[2], 1);
  __syncthreads();
  if (t == 0) {
    int m;
    if      (cnt[1] >= 240) m = 1;
    else if (cnt[2] >= 240) m = 2;
    else                    m = 0;
    mode_out[0] = m;
  }
}

// ---------------------------------------------------------------------------
// Pre-pass 1: x f32 -> fp16, PERMUTED within each 8-chunk to the dequant's
// register order [x0,x4,x1,x5,x2,x6,x3,x7]. Exact (x was fp16 originally).
// ---------------------------------------------------------------------------
__global__ __launch_bounds__(256) void convert_x_kernel(
    const float* __restrict__ xf, u16* __restrict__ xh,
    const int* __restrict__ modep) {
  if (modep && modep[0] != 0) return;
  const int total8 = M_DIM * (K_DIM / 8);   // 4,194,304 chunks
  int idx = blockIdx.x * 256 + threadIdx.x;
  const int stride = gridDim.x * 256;
  for (; idx < total8; idx += stride) {
    const float4* p = (const float4*)(xf + (size_t)idx * 8);
    float4 a = p[0], b = p[1];
    union { _Float16 h[8]; s16x8 v; } r;
    r.h[0] = (_Float16)a.x; r.h[1] = (_Float16)b.x;   // (x0, x4)
    r.h[2] = (_Float16)a.y; r.h[3] = (_Float16)b.y;   // (x1, x5)
    r.h[4] = (_Float16)a.z; r.h[5] = (_Float16)b.z;   // (x2, x6)
    r.h[6] = (_Float16)a.w; r.h[7] = (_Float16)b.w;   // (x3, x7)
    *(s16x8*)(xh + (size_t)idx * 8) = r.v;
  }
}

// ---------------------------------------------------------------------------
// Pre-pass 2: compact W: 4 int32 (1 payload byte each) -> 1 dword of 8
// nibbles. Row stride = K/8 = 512 dwords. wq[col*512 + d]: nibble n = k d*8+n.
// ---------------------------------------------------------------------------
__global__ __launch_bounds__(256) void repack_w_kernel(
    const int* __restrict__ packed, u32* __restrict__ wq) {
  const int total = N_DIM * WQROW;          // 5,636,096 dwords
  int idx = blockIdx.x * 256 + threadIdx.x;
  const int stride = gridDim.x * 256;
  for (; idx < total; idx += stride) {
    const int4 p = ((const int4*)packed)[idx];
    wq[idx] = (u32)(p.x & 255) | ((u32)(p.y & 255) << 8) |
              ((u32)(p.z & 255) << 16) | ((u32)p.w << 24);
  }
}

// ---------------------------------------------------------------------------
// Dequant 8 weights from one nibble-dword. Register fp16 order:
// (k0,k4),(k1,k5),(k2,k6),(k3,k7) — matched by the permuted x layout.
// (1024+nib) - 1032 = nib-8 exact in fp16; * s (exact fp16) -> ref-exact W.
// ---------------------------------------------------------------------------
__device__ __forceinline__ f16x8 dq8(u32 q, h2 s2) {
  const u32 M = 0x000F000Fu, G = 0x64006400u;
  const h2 bias = {(_Float16)(-1032.0f), (_Float16)(-1032.0f)};
  union { u32 u; h2 h; } a0, a1, a2, a3;
  a0.u = (q & M) | G;
  a1.u = ((q >> 4) & M) | G;
  a2.u = ((q >> 8) & M) | G;
  a3.u = ((q >> 12) & M) | G;
  a0.h = (a0.h + bias) * s2;
  a1.h = (a1.h + bias) * s2;
  a2.h = (a2.h + bias) * s2;
  a3.h = (a3.h + bias) * s2;
  union { u32 u[4]; f16x8 f; } r;
  r.u[0] = a0.u; r.u[1] = a1.u; r.u[2] = a2.u; r.u[3] = a3.u;
  return r.f;
}

// ---------------------------------------------------------------------------
// FAST PATH (mode 0): BM=128, BN=256, BK=64; 4 waves 1x4 in n, each wave
// 128x64 (acc 8x4). R8: 256-thread blocks + 32 KiB LDS so TWO independent
// blocks co-reside per CU (R7 had one 512-thread block/CU -> every barrier's
// vmcnt(0) drain stalled the whole CU). A: global_load_lds dbuf + XOR
// swizzle; B: one compact dword per fragment, in-register dequant.
// ---------------------------------------------------------------------------
__global__ __launch_bounds__(256, 2) void q4gemm_fast_kernel(
    const u16* __restrict__ xh,      // fp16, permuted 8-chunks
    const u32* __restrict__ wq,      // compact nibbles [N][512]
    const float* __restrict__ scf,   // f32 scales [N][32]
    float* __restrict__ out,
    const int* __restrict__ modep)
{
  if (modep && modep[0] != 0) return;

  __shared__ _Float16 As[2][128 * 64];   // 32 KiB total

  const int tid  = threadIdx.x;
  const int lane = tid & 63;
  const int wv   = tid >> 6;             // 0..3
  const int wn   = wv * 64;              // 4 waves along n
  const int ln15 = lane & 15;
  const int lk   = lane >> 4;            // 0..3

  // XCD swizzle: 2752 = 8 * 344; bm-fastest so same-XCD neighbors share the
  // B panel (~0.5 MB) in L2.  bm in [0,64), bn in [0,43).
  int bid = blockIdx.x;
  int f   = (bid & 7) * 344 + (bid >> 3);
  int bn  = f / 64;
  int bm  = f - bn * 64;
  const int m0 = bm * 128;
  const int n0 = bn * 256;

  // ---- A staging addresses: LDS[row][slot] = G[row][slot ^ (row&7)]
  const u16* abase[4];
  #pragma unroll
  for (int q = 0; q < 4; ++q) {
    int row = q * 32 + wv * 8 + (lane >> 3);
    abase[q] = xh + (size_t)(m0 + row) * K_DIM + (((lane & 7) ^ (lane >> 3)) * 8);
  }

#define STAGE(BUF, T) do { \
    _Pragma("unroll") \
    for (int q = 0; q < 4; ++q) \
      __builtin_amdgcn_global_load_lds( \
          (const __attribute__((address_space(1))) void*)(abase[q] + (T) * 64), \
          (__attribute__((address_space(3))) void*)(&As[BUF][q * 2048 + wv * 512]), \
          16, 0, 0); \
  } while (0)

  // ---- B/scale addresses (row stride 512 dwords)
  int pcol[4], scol[4];
  #pragma unroll
  for (int j = 0; j < 4; ++j) {
    int col = n0 + wn + j * 16 + ln15;
    pcol[j] = col * WQROW + lk;          // dword index into wq
    scol[j] = col * GROUPS;
  }

  f32x4 acc[8][4];
  #pragma unroll
  for (int i = 0; i < 8; ++i)
    #pragma unroll
    for (int j = 0; j < 4; ++j)
      acc[i][j] = f32x4{0.f, 0.f, 0.f, 0.f};

  // ---- prologue
  STAGE(0, 0);
  u32 rA0[4], rA1[4], rB0[4], rB1[4];
  #pragma unroll
  for (int j = 0; j < 4; ++j) {
    rA0[j] = wq[pcol[j]];
    rA1[j] = wq[pcol[j] + 4];
  }
  float snextf[4];
  #pragma unroll
  for (int j = 0; j < 4; ++j) snextf[j] = scf[scol[j]];
  __syncthreads();

  for (int g = 0; g < GROUPS; ++g) {
    h2 s2[4];
    #pragma unroll
    for (int j = 0; j < 4; ++j) {
      _Float16 sh = (_Float16)snextf[j];
      s2[j] = h2{sh, sh};
    }
    if (g < GROUPS - 1) {
      #pragma unroll
      for (int j = 0; j < 4; ++j) snextf[j] = scf[scol[j] + g + 1];
    }

    // ================= phase A: t = 2g (As[0], rA) =================
    {
      const int t = 2 * g;
      STAGE(1, t + 1);                       // t+1 <= 63 always
      #pragma unroll
      for (int j = 0; j < 4; ++j) {          // prefetch B for tile t+1 (phase B)
        rB0[j] = wq[pcol[j] + (t + 1) * 8];
        rB1[j] = wq[pcol[j] + (t + 1) * 8 + 4];
      }
      #pragma unroll
      for (int kkc = 0; kkc < 2; ++kkc) {
        f16x8 bf0 = dq8(kkc ? rA1[0] : rA0[0], s2[0]);
        f16x8 bf1 = dq8(kkc ? rA1[1] : rA0[1], s2[1]);
        f16x8 bf2 = dq8(kkc ? rA1[2] : rA0[2], s2[2]);
        f16x8 bf3 = dq8(kkc ? rA1[3] : rA0[3], s2[3]);
        #pragma unroll
        for (int i = 0; i < 8; ++i) {
          const int row  = i * 16 + ln15;
          const int slot = (kkc * 4 + lk) ^ (ln15 & 7);
          f16x8 af = *(const f16x8*)&As[0][row * 64 + slot * 8];
          acc[i][0] = __builtin_amdgcn_mfma_f32_16x16x32_f16(af, bf0, acc[i][0], 0, 0, 0);
          acc[i][1] = __builtin_amdgcn_mfma_f32_16x16x32_f16(af, bf1, acc[i][1], 0, 0, 0);
          acc[i][2] = __builtin_amdgcn_mfma_f32_16x16x32_f16(af, bf2, acc[i][2], 0, 0, 0);
          acc[i][3] = __builtin_amdgcn_mfma_f32_16x16x32_f16(af, bf3, acc[i][3], 0, 0, 0);
        }
      }
      __syncthreads();
    }

    // ================= phase B: t = 2g+1 (As[1], rB) =================
    {
      const int t = 2 * g + 1;
      if (t < 63) STAGE(0, t + 1);
      const int tn = (t + 1 <= 63) ? (t + 1) : 0;   // next phase A's tile
      #pragma unroll
      for (int j = 0; j < 4; ++j) {                 // prefetch B for tile t+1
        rA0[j] = wq[pcol[j] + tn * 8];
        rA1[j] = wq[pcol[j] + tn * 8 + 4];
      }
      #pragma unroll
      for (int kkc = 0; kkc < 2; ++kkc) {
        f16x8 bf0 = dq8(kkc ? rB1[0] : rB0[0], s2[0]);
        f16x8 bf1 = dq8(kkc ? rB1[1] : rB0[1], s2[1]);
        f16x8 bf2 = dq8(kkc ? rB1[2] : rB0[2], s2[2]);
        f16x8 bf3 = dq8(kkc ? rB1[3] : rB0[3], s2[3]);
        #pragma unroll
        for (int i = 0; i < 8; ++i) {
          const int row  = i * 16 + ln15;
          const int slot = (kkc * 4 + lk) ^ (ln15 & 7);
          f16x8 af = *(const f16x8*)&As[1][row * 64 + slot * 8];
          acc[i][0] = __builtin_amdgcn_mfma_f32_16x16x32_f16(af, bf0, acc[i][0], 0, 0, 0);
          acc[i][1] = __builtin_amdgcn_mfma_f32_16x16x32_f16(af, bf1, acc[i][1], 0, 0, 0);
          acc[i][2] = __builtin_amdgcn_mfma_f32_16x16x32_f16(af, bf2, acc[i][2], 0, 0, 0);
          acc[i][3] = __builtin_amdgcn_mfma_f32_16x16x32_f16(af, bf3, acc[i][3], 0, 0, 0);
        }
      }
      __syncthreads();
    }
  }

  // ---- epilogue: C/D col=lane&15, row=(lane>>4)*4+reg
  #pragma unroll
  for (int i = 0; i < 8; ++i) {
    int r0 = m0 + i * 16 + (lane >> 4) * 4;
    #pragma unroll
    for (int j = 0; j < 4; ++j) {
      int cc = n0 + wn + j * 16 + ln15;
      #pragma unroll
      for (int r = 0; r < 4; ++r)
        out[(size_t)(r0 + r) * N_DIM + cc] = acc[i][j][r];
    }
  }
#undef STAGE
}

// ---------------------------------------------------------------------------
// SLOW FALLBACK (any mode; skips mode 0 when fast path ran).
// ---------------------------------------------------------------------------
__global__ __launch_bounds__(256) void q4gemm_slow_kernel(
    const void* __restrict__ xraw,
    const int*  __restrict__ packed,
    const void* __restrict__ scraw,
    float* __restrict__ out,
    const int* __restrict__ modep,
    int skip0)
{
  const int mode = modep ? modep[0] : 0;
  if (skip0 && mode == 0) return;

  __shared__ u16 Asl[128 * LDSK];
  __shared__ u16 Bsl[128 * LDSK];

  const int tid  = threadIdx.x;
  const int lane = tid & 63;
  const int wv   = tid >> 6;
  const int wm   = (wv >> 1) * 64;
  const int wn   = (wv & 1) * 64;
  const int n0   = blockIdx.x * 128;
  const int m0   = blockIdx.y * 128;

  f32x4 acc[4][4];
  #pragma unroll
  for (int i = 0; i < 4; ++i)
    #pragma unroll
    for (int j = 0; j < 4; ++j)
      acc[i][j] = f32x4{0.f, 0.f, 0.f, 0.f};

  const int lrow16 = lane & 15;
  const int lk8    = (lane >> 4) * 8;

  for (int k0 = 0; k0 < K_DIM; k0 += 64) {
    if (mode == 0) {
      const float* xf = (const float*)xraw;
      #pragma unroll
      for (int it = 0; it < 4; ++it) {
        int s = tid + it * 256;
        int row = s >> 3, c8 = (s & 7) * 8;
        const float4* p = (const float4*)(xf + (size_t)(m0 + row) * K_DIM + k0 + c8);
        float4 v0 = p[0], v1 = p[1];
        u16 tmp[8] = { f2bf(v0.x), f2bf(v0.y), f2bf(v0.z), f2bf(v0.w),
                       f2bf(v1.x), f2bf(v1.y), f2bf(v1.z), f2bf(v1.w) };
        *(s16x8*)&Asl[row * LDSK + c8] = *(const s16x8*)tmp;
      }
    } else if (mode == 1) {
      const u16* xhh = (const u16*)xraw;
      #pragma unroll
      for (int it = 0; it < 4; ++it) {
        int s = tid + it * 256;
        int row = s >> 3, c8 = (s & 7) * 8;
        s16x8 v = *(const s16x8*)(xhh + (size_t)(m0 + row) * K_DIM + k0 + c8);
        u16 tmp[8];
        #pragma unroll
        for (int j = 0; j < 8; ++j) tmp[j] = f2bf(h2f((u16)v[j]));
        *(s16x8*)&Asl[row * LDSK + c8] = *(const s16x8*)tmp;
      }
    } else {
      const u16* xhh = (const u16*)xraw;
      #pragma unroll
      for (int it = 0; it < 4; ++it) {
        int s = tid + it * 256;
        int row = s >> 3, c8 = (s & 7) * 8;
        s16x8 v = *(const s16x8*)(xhh + (size_t)(m0 + row) * K_DIM + k0 + c8);
        *(s16x8*)&Asl[row * LDSK + c8] = v;
      }
    }

    {
      int row  = tid >> 1;
      int half = tid & 1;
      int srw  = n0 + row;
      int g    = k0 >> 7;
      float scale;
      if      (mode == 0) scale = ((const float*)scraw)[(size_t)srw * GROUPS + g];
      else if (mode == 1) scale = h2f(((const u16*)scraw)[(size_t)srw * GROUPS + g]);
      else                scale = bf2f(((const u16*)scraw)[(size_t)srw * GROUPS + g]);

      const int4* pp = (const int4*)(packed + (size_t)srw * (K_DIM / 2) + (k0 >> 1) + half * 16);
      #pragma unroll
      for (int j = 0; j < 4; ++j) {
        int4 pv = pp[j];
        int vals[4] = {pv.x, pv.y, pv.z, pv.w};
        u16 w[8];
        #pragma unroll
        for (int e = 0; e < 4; ++e) {
          int b = vals[e] & 255;
          w[e * 2]     = f2bf(scale * (float)((b & 15) - 8));
          w[e * 2 + 1] = f2bf(scale * (float)(((b >> 4) & 15) - 8));
        }
        int i0 = half * 16 + j * 4;
        *(s16x8*)&Bsl[row * LDSK + i0 * 2] = *(const s16x8*)w;
      }
    }
    __syncthreads();

    #pragma unroll
    for (int kk = 0; kk < 64; kk += 32) {
      s16x8 af[4], bfr[4];
      int klane = kk + lk8;
      #pragma unroll
      for (int i = 0; i < 4; ++i)
        af[i] = *(const s16x8*)&Asl[(wm + i * 16 + lrow16) * LDSK + klane];
      #pragma unroll
      for (int i = 0; i < 4; ++i)
        bfr[i] = *(const s16x8*)&Bsl[(wn + i * 16 + lrow16) * LDSK + klane];
      #pragma unroll
      for (int i = 0; i < 4; ++i)
        #pragma unroll
        for (int j = 0; j < 4; ++j)
          acc[i][j] = __builtin_amdgcn_mfma_f32_16x16x32_bf16(af[i], bfr[j], acc[i][j], 0, 0, 0);
    }
    __syncthreads();
  }

  #pragma unroll
  for (int i = 0; i < 4; ++i) {
    int rbase = m0 + wm + i * 16 + ((lane >> 4) * 4);
    #pragma unroll
    for (int j = 0; j < 4; ++j) {
      int c = n0 + wn + j * 16 + (lane & 15);
      #pragma unroll
      for (int r = 0; r < 4; ++r)
        out[(size_t)(rbase + r) * N_DIM + c] = acc[i][j][r];
    }
  }
}

extern "C" void kernel_launch(void* const* d_in, const int* in_sizes, int n_in,
                              void* d_out, int out_size, void* d_ws, size_t ws_size,
                              hipStream_t stream) {
  const void* x      = d_in[0];
  const int*  packed = (const int*)d_in[1];
  const void* scales = d_in[2];
  float* out = (float*)d_out;

  const size_t XB = (size_t)M_DIM * K_DIM * 2;        // 67,108,864 B
  const size_t WQ = (size_t)N_DIM * WQROW * 4;        // 22,544,384 B
  const size_t NEED = 256 + XB + WQ;

  int* mode_flag = nullptr;
  if (ws_size >= 4) {
    mode_flag = (int*)d_ws;
    probe_mode_kernel<<<dim3(1), dim3(256), 0, stream>>>(scales, mode_flag);
  }

  int fast_ok = (ws_size >= NEED && mode_flag) ? 1 : 0;

  if (fast_ok) {
    u16* xh = (u16*)((char*)d_ws + 256);
    u32* wq = (u32*)((char*)d_ws + 256 + XB);
    convert_x_kernel<<<dim3(2048), dim3(256), 0, stream>>>(
        (const float*)x, xh, mode_flag);
    repack_w_kernel<<<dim3(2048), dim3(256), 0, stream>>>(packed, wq);
    q4gemm_fast_kernel<<<dim3(2752), dim3(256), 0, stream>>>(
        xh, wq, (const float*)scales, out, mode_flag);
  }

  q4gemm_slow_kernel<<<dim3(N_DIM / 128, M_DIM / 128), dim3(256), 0, stream>>>(
      x, packed, scales, out, mode_flag, fast_ok);
}

// Round 10
// 1053.778 us; speedup vs baseline: 2.0170x; 1.3285x over previous
//
#include <hip/hip_runtime.h>

#define M_DIM 8192
#define N_DIM 11008
#define K_DIM 4096
#define GROUPS 32     // K / 128
#define WQROW 512     // dwords per row of compact W = K/8
#define LDSK 72       // slow kernel pad

typedef short s16x8 __attribute__((ext_vector_type(8)));
typedef _Float16 f16x8 __attribute__((ext_vector_type(8)));
typedef _Float16 h2 __attribute__((ext_vector_type(2)));
typedef float f32x4 __attribute__((ext_vector_type(4)));
typedef unsigned short u16;
typedef unsigned int u32;

union f32u { float f; unsigned u; };
union h16u { u16 u; _Float16 h; };

__device__ __forceinline__ u16 f2bf(float f) {
  f32u v; v.f = f;
  unsigned r = v.u + 0x7FFFu + ((v.u >> 16) & 1u);  // RNE
  return (u16)(r >> 16);
}
__device__ __forceinline__ float bf2f(u16 b) {
  f32u v; v.u = ((unsigned)b) << 16; return v.f;
}
__device__ __forceinline__ float h2f(u16 b) {
  h16u v; v.u = b; return (float)v.h;
}

// ---------------------------------------------------------------------------
// Probe (R3/R4 empirics: harness promotes fp16 -> f32 => mode 0).
// ---------------------------------------------------------------------------
__global__ void probe_mode_kernel(const void* __restrict__ scales,
                                  int* __restrict__ mode_out) {
  __shared__ int cnt[3];
  int t = threadIdx.x;
  if (t < 3) cnt[t] = 0;
  __syncthreads();
  float f0 = ((const float*)scales)[t];
  u16  hu  = ((const u16*)scales)[t];
  float f1 = h2f(hu);
  float f2 = bf2f(hu);
  if (f0 > 0.0004f && f0 < 0.065f) atomicAdd(&cnt[0], 1);
  if (f1 > 0.0004f && f1 < 0.065f) atomicAdd(&cnt[1], 1);
  if (f2 > 0.0004f && f2 < 0.065f) atomicAdd(&cnt[2], 1);
  __syncthreads();
  if (t == 0) {
    int m;
    if      (cnt[1] >= 240) m = 1;
    else if (cnt[2] >= 240) m = 2;
    else                    m = 0;
    mode_out[0] = m;
  }
}

// ---------------------------------------------------------------------------
// Pre-pass 1: x f32 -> fp16, PERMUTED within each 8-chunk to the dequant's
// register order [x0,x4,x1,x5,x2,x6,x3,x7]. Exact (x was fp16 originally).
// ---------------------------------------------------------------------------
__global__ __launch_bounds__(256) void convert_x_kernel(
    const float* __restrict__ xf, u16* __restrict__ xh,
    const int* __restrict__ modep) {
  if (modep && modep[0] != 0) return;
  const int total8 = M_DIM * (K_DIM / 8);   // 4,194,304 chunks
  int idx = blockIdx.x * 256 + threadIdx.x;
  const int stride = gridDim.x * 256;
  for (; idx < total8; idx += stride) {
    const float4* p = (const float4*)(xf + (size_t)idx * 8);
    float4 a = p[0], b = p[1];
    union { _Float16 h[8]; s16x8 v; } r;
    r.h[0] = (_Float16)a.x; r.h[1] = (_Float16)b.x;   // (x0, x4)
    r.h[2] = (_Float16)a.y; r.h[3] = (_Float16)b.y;   // (x1, x5)
    r.h[4] = (_Float16)a.z; r.h[5] = (_Float16)b.z;   // (x2, x6)
    r.h[6] = (_Float16)a.w; r.h[7] = (_Float16)b.w;   // (x3, x7)
    *(s16x8*)(xh + (size_t)idx * 8) = r.v;
  }
}

// ---------------------------------------------------------------------------
// Pre-pass 2: compact W: 4 int32 (1 payload byte each) -> 1 dword of 8
// nibbles. Row stride = K/8 = 512 dwords. wq[col*512 + d]: nibble n = k d*8+n.
// ---------------------------------------------------------------------------
__global__ __launch_bounds__(256) void repack_w_kernel(
    const int* __restrict__ packed, u32* __restrict__ wq) {
  const int total = N_DIM * WQROW;          // 5,636,096 dwords
  int idx = blockIdx.x * 256 + threadIdx.x;
  const int stride = gridDim.x * 256;
  for (; idx < total; idx += stride) {
    const int4 p = ((const int4*)packed)[idx];
    wq[idx] = (u32)(p.x & 255) | ((u32)(p.y & 255) << 8) |
              ((u32)(p.z & 255) << 16) | ((u32)p.w << 24);
  }
}

// ---------------------------------------------------------------------------
// Dequant 8 weights from one nibble-dword. Register fp16 order:
// (k0,k4),(k1,k5),(k2,k6),(k3,k7) — matched by the permuted x layout.
// (1024+nib) - 1032 = nib-8 exact in fp16; * s (exact fp16) -> ref-exact W.
// ---------------------------------------------------------------------------
__device__ __forceinline__ f16x8 dq8(u32 q, h2 s2) {
  const u32 M = 0x000F000Fu, G = 0x64006400u;
  const h2 bias = {(_Float16)(-1032.0f), (_Float16)(-1032.0f)};
  union { u32 u; h2 h; } a0, a1, a2, a3;
  a0.u = (q & M) | G;
  a1.u = ((q >> 4) & M) | G;
  a2.u = ((q >> 8) & M) | G;
  a3.u = ((q >> 12) & M) | G;
  a0.h = (a0.h + bias) * s2;
  a1.h = (a1.h + bias) * s2;
  a2.h = (a2.h + bias) * s2;
  a3.h = (a3.h + bias) * s2;
  union { u32 u[4]; f16x8 f; } r;
  r.u[0] = a0.u; r.u[1] = a1.u; r.u[2] = a2.u; r.u[3] = a3.u;
  return r.f;
}

// ---------------------------------------------------------------------------
// FAST PATH (mode 0): BM=128, BN=256, BK=64; 4 waves 1x4 in n, acc 8x4.
// R10: ORDER-ROBUST counted-vmcnt pipeline.
//  - 3 LDS buffers, STAGE 2 tiles ahead; one s_barrier + s_waitcnt vmcnt(12)
//    per tile-phase. Safety: vmcnt retires oldest-first, so STAGE(T)
//    (issued phase T-2) is complete at phase T's wait iff >=12 ops were
//    issued after it — the intervening phase always issues >=12, so this
//    holds under ANY intra-phase compiler reordering (R9's race).
//  - Register loads (B dwords, scales) need no manual waits: compiler
//    auto-inserts waits on register deps. Only the global_load_lds ->LDS->
//    ds_read dependency (invisible to the compiler) is hand-counted.
//  - Last tile (63): preceded by a 4-op phase -> one-time vmcnt(0).
// ---------------------------------------------------------------------------
__global__ __launch_bounds__(256, 2) void q4gemm_fast_kernel(
    const u16* __restrict__ xh,      // fp16, permuted 8-chunks
    const u32* __restrict__ wq,      // compact nibbles [N][512]
    const float* __restrict__ scf,   // f32 scales [N][32]
    float* __restrict__ out,
    const int* __restrict__ modep)
{
  if (modep && modep[0] != 0) return;

  __shared__ _Float16 As[3][128 * 64];   // 48 KiB

  const int tid  = threadIdx.x;
  const int lane = tid & 63;
  const int wv   = tid >> 6;             // 0..3
  const int wn   = wv * 64;              // 4 waves along n
  const int ln15 = lane & 15;
  const int lk   = lane >> 4;            // 0..3

  // XCD swizzle: 2752 = 8 * 344; bm-fastest so same-XCD neighbors share the
  // B panel in L2.  bm in [0,64), bn in [0,43).
  int bid = blockIdx.x;
  int f   = (bid & 7) * 344 + (bid >> 3);
  int bn  = f / 64;
  int bm  = f - bn * 64;
  const int m0 = bm * 128;
  const int n0 = bn * 256;

  // ---- A staging addresses: LDS[row][slot] = G[row][slot ^ (row&7)]
  const u16* abase[4];
  #pragma unroll
  for (int q = 0; q < 4; ++q) {
    int row = q * 32 + wv * 8 + (lane >> 3);
    abase[q] = xh + (size_t)(m0 + row) * K_DIM + (((lane & 7) ^ (lane >> 3)) * 8);
  }

#define STAGE(PB, T) do { \
    _Float16* dst = &As[(PB)][0]; \
    _Pragma("unroll") \
    for (int q = 0; q < 4; ++q) \
      __builtin_amdgcn_global_load_lds( \
          (const __attribute__((address_space(1))) void*)(abase[q] + (T) * 64), \
          (__attribute__((address_space(3))) void*)(dst + q * 2048 + wv * 512), \
          16, 0, 0); \
  } while (0)

#define LOADB(RB, T) do { \
    _Pragma("unroll") \
    for (int j = 0; j < 4; ++j) { \
      RB[j]     = wq[pcol[j] + (T) * 8]; \
      RB[j + 4] = wq[pcol[j] + (T) * 8 + 4]; \
    } \
  } while (0)

#define COMPUTE(RB, PB) do { \
    const _Float16* asb = &As[(PB)][0]; \
    _Pragma("unroll") \
    for (int kkc = 0; kkc < 2; ++kkc) { \
      f16x8 bfr0 = dq8(RB[kkc * 4 + 0], s2[0]); \
      f16x8 bfr1 = dq8(RB[kkc * 4 + 1], s2[1]); \
      f16x8 bfr2 = dq8(RB[kkc * 4 + 2], s2[2]); \
      f16x8 bfr3 = dq8(RB[kkc * 4 + 3], s2[3]); \
      _Pragma("unroll") \
      for (int i = 0; i < 8; ++i) { \
        const int row  = i * 16 + ln15; \
        const int slot = (kkc * 4 + lk) ^ (ln15 & 7); \
        f16x8 af = *(const f16x8*)&asb[row * 64 + slot * 8]; \
        acc[i][0] = __builtin_amdgcn_mfma_f32_16x16x32_f16(af, bfr0, acc[i][0], 0, 0, 0); \
        acc[i][1] = __builtin_amdgcn_mfma_f32_16x16x32_f16(af, bfr1, acc[i][1], 0, 0, 0); \
        acc[i][2] = __builtin_amdgcn_mfma_f32_16x16x32_f16(af, bfr2, acc[i][2], 0, 0, 0); \
        acc[i][3] = __builtin_amdgcn_mfma_f32_16x16x32_f16(af, bfr3, acc[i][3], 0, 0, 0); \
      } \
    } \
  } while (0)

  // ---- B/scale addresses (row stride 512 dwords)
  int pcol[4], scol[4];
  #pragma unroll
  for (int j = 0; j < 4; ++j) {
    int col = n0 + wn + j * 16 + ln15;
    pcol[j] = col * WQROW + lk;          // dword index into wq
    scol[j] = col * GROUPS;
  }

  f32x4 acc[8][4];
  #pragma unroll
  for (int i = 0; i < 8; ++i)
    #pragma unroll
    for (int j = 0; j < 4; ++j)
      acc[i][j] = f32x4{0.f, 0.f, 0.f, 0.f};

  u32 rbE[8], rbO[8];
  float snextf[4];
  h2 s2[4];

  // ---- prologue: stage tiles 0,1; B(0),B(1); scales g=0; full drain once.
  STAGE(0, 0);
  STAGE(1, 1);
  LOADB(rbE, 0);
  LOADB(rbO, 1);
  #pragma unroll
  for (int j = 0; j < 4; ++j) snextf[j] = scf[scol[j]];
  asm volatile("s_waitcnt vmcnt(0)" ::: "memory");

  int p0 = 0, p1 = 1, p2 = 2;

  for (int tp = 0; tp < 32; ++tp) {
    const int t0 = 2 * tp;
    const int t1 = t0 + 1;

    // ============== even phase: tile t0, buf p0, rbE ==============
    asm volatile("s_waitcnt vmcnt(12)" ::: "memory");
    __builtin_amdgcn_s_barrier();
    __builtin_amdgcn_sched_barrier(0);

    #pragma unroll
    for (int j = 0; j < 4; ++j) {        // group tp scales -> packed fp16
      _Float16 sh = (_Float16)snextf[j];
      s2[j] = h2{sh, sh};
    }
    if (t0 + 2 < 64) STAGE(p2, t0 + 2);

    __builtin_amdgcn_s_setprio(1);
    COMPUTE(rbE, p0);
    __builtin_amdgcn_s_setprio(0);

    if (t0 + 2 < 64) LOADB(rbE, t0 + 2);
    {
      const int gn = (tp + 1 > 31) ? 31 : (tp + 1);
      #pragma unroll
      for (int j = 0; j < 4; ++j) snextf[j] = scf[scol[j] + gn];
    }

    // ============== odd phase: tile t1, buf p1, rbO ==============
    if (tp == 31) {
      asm volatile("s_waitcnt vmcnt(0)" ::: "memory");   // tail: prev phase issued only 4
    } else {
      asm volatile("s_waitcnt vmcnt(12)" ::: "memory");
    }
    __builtin_amdgcn_s_barrier();
    __builtin_amdgcn_sched_barrier(0);

    if (t1 + 2 < 64) STAGE(p0, t1 + 2);

    __builtin_amdgcn_s_setprio(1);
    COMPUTE(rbO, p1);
    __builtin_amdgcn_s_setprio(0);

    if (t1 + 2 < 64) LOADB(rbO, t1 + 2);

    // rotate buffers: next pair reads (p2, p0), stages (p1, p2')
    int tmp = p2; p2 = p1; p1 = p0; p0 = tmp;
  }

  // ---- epilogue: C/D col=lane&15, row=(lane>>4)*4+reg
  #pragma unroll
  for (int i = 0; i < 8; ++i) {
    int r0 = m0 + i * 16 + (lane >> 4) * 4;
    #pragma unroll
    for (int j = 0; j < 4; ++j) {
      int cc = n0 + wn + j * 16 + ln15;
      #pragma unroll
      for (int r = 0; r < 4; ++r)
        out[(size_t)(r0 + r) * N_DIM + cc] = acc[i][j][r];
    }
  }
#undef STAGE
#undef LOADB
#undef COMPUTE
}

// ---------------------------------------------------------------------------
// SLOW FALLBACK (any mode; skips mode 0 when fast path ran).
// ---------------------------------------------------------------------------
__global__ __launch_bounds__(256) void q4gemm_slow_kernel(
    const void* __restrict__ xraw,
    const int*  __restrict__ packed,
    const void* __restrict__ scraw,
    float* __restrict__ out,
    const int* __restrict__ modep,
    int skip0)
{
  const int mode = modep ? modep[0] : 0;
  if (skip0 && mode == 0) return;

  __shared__ u16 Asl[128 * LDSK];
  __shared__ u16 Bsl[128 * LDSK];

  const int tid  = threadIdx.x;
  const int lane = tid & 63;
  const int wv   = tid >> 6;
  const int wm   = (wv >> 1) * 64;
  const int wn   = (wv & 1) * 64;
  const int n0   = blockIdx.x * 128;
  const int m0   = blockIdx.y * 128;

  f32x4 acc[4][4];
  #pragma unroll
  for (int i = 0; i < 4; ++i)
    #pragma unroll
    for (int j = 0; j < 4; ++j)
      acc[i][j] = f32x4{0.f, 0.f, 0.f, 0.f};

  const int lrow16 = lane & 15;
  const int lk8    = (lane >> 4) * 8;

  for (int k0 = 0; k0 < K_DIM; k0 += 64) {
    if (mode == 0) {
      const float* xf = (const float*)xraw;
      #pragma unroll
      for (int it = 0; it < 4; ++it) {
        int s = tid + it * 256;
        int row = s >> 3, c8 = (s & 7) * 8;
        const float4* p = (const float4*)(xf + (size_t)(m0 + row) * K_DIM + k0 + c8);
        float4 v0 = p[0], v1 = p[1];
        u16 tmp[8] = { f2bf(v0.x), f2bf(v0.y), f2bf(v0.z), f2bf(v0.w),
                       f2bf(v1.x), f2bf(v1.y), f2bf(v1.z), f2bf(v1.w) };
        *(s16x8*)&Asl[row * LDSK + c8] = *(const s16x8*)tmp;
      }
    } else if (mode == 1) {
      const u16* xhh = (const u16*)xraw;
      #pragma unroll
      for (int it = 0; it < 4; ++it) {
        int s = tid + it * 256;
        int row = s >> 3, c8 = (s & 7) * 8;
        s16x8 v = *(const s16x8*)(xhh + (size_t)(m0 + row) * K_DIM + k0 + c8);
        u16 tmp[8];
        #pragma unroll
        for (int j = 0; j < 8; ++j) tmp[j] = f2bf(h2f((u16)v[j]));
        *(s16x8*)&Asl[row * LDSK + c8] = *(const s16x8*)tmp;
      }
    } else {
      const u16* xhh = (const u16*)xraw;
      #pragma unroll
      for (int it = 0; it < 4; ++it) {
        int s = tid + it * 256;
        int row = s >> 3, c8 = (s & 7) * 8;
        s16x8 v = *(const s16x8*)(xhh + (size_t)(m0 + row) * K_DIM + k0 + c8);
        *(s16x8*)&Asl[row * LDSK + c8] = v;
      }
    }

    {
      int row  = tid >> 1;
      int half = tid & 1;
      int srw  = n0 + row;
      int g    = k0 >> 7;
      float scale;
      if      (mode == 0) scale = ((const float*)scraw)[(size_t)srw * GROUPS + g];
      else if (mode == 1) scale = h2f(((const u16*)scraw)[(size_t)srw * GROUPS + g]);
      else                scale = bf2f(((const u16*)scraw)[(size_t)srw * GROUPS + g]);

      const int4* pp = (const int4*)(packed + (size_t)srw * (K_DIM / 2) + (k0 >> 1) + half * 16);
      #pragma unroll
      for (int j = 0; j < 4; ++j) {
        int4 pv = pp[j];
        int vals[4] = {pv.x, pv.y, pv.z, pv.w};
        u16 w[8];
        #pragma unroll
        for (int e = 0; e < 4; ++e) {
          int b = vals[e] & 255;
          w[e * 2]     = f2bf(scale * (float)((b & 15) - 8));
          w[e * 2 + 1] = f2bf(scale * (float)(((b >> 4) & 15) - 8));
        }
        int i0 = half * 16 + j * 4;
        *(s16x8*)&Bsl[row * LDSK + i0 * 2] = *(const s16x8*)w;
      }
    }
    __syncthreads();

    #pragma unroll
    for (int kk = 0; kk < 64; kk += 32) {
      s16x8 af[4], bfr[4];
      int klane = kk + lk8;
      #pragma unroll
      for (int i = 0; i < 4; ++i)
        af[i] = *(const s16x8*)&Asl[(wm + i * 16 + lrow16) * LDSK + klane];
      #pragma unroll
      for (int i = 0; i < 4; ++i)
        bfr[i] = *(const s16x8*)&Bsl[(wn + i * 16 + lrow16) * LDSK + klane];
      #pragma unroll
      for (int i = 0; i < 4; ++i)
        #pragma unroll
        for (int j = 0; j < 4; ++j)
          acc[i][j] = __builtin_amdgcn_mfma_f32_16x16x32_bf16(af[i], bfr[j], acc[i][j], 0, 0, 0);
    }
    __syncthreads();
  }

  #pragma unroll
  for (int i = 0; i < 4; ++i) {
    int rbase = m0 + wm + i * 16 + ((lane >> 4) * 4);
    #pragma unroll
    for (int j = 0; j < 4; ++j) {
      int c = n0 + wn + j * 16 + (lane & 15);
      #pragma unroll
      for (int r = 0; r < 4; ++r)
        out[(size_t)(rbase + r) * N_DIM + c] = acc[i][j][r];
    }
  }
}

extern "C" void kernel_launch(void* const* d_in, const int* in_sizes, int n_in,
                              void* d_out, int out_size, void* d_ws, size_t ws_size,
                              hipStream_t stream) {
  const void* x      = d_in[0];
  const int*  packed = (const int*)d_in[1];
  const void* scales = d_in[2];
  float* out = (float*)d_out;

  const size_t XB = (size_t)M_DIM * K_DIM * 2;        // 67,108,864 B
  const size_t WQ = (size_t)N_DIM * WQROW * 4;        // 22,544,384 B
  const size_t NEED = 256 + XB + WQ;

  int* mode_flag = nullptr;
  if (ws_size >= 4) {
    mode_flag = (int*)d_ws;
    probe_mode_kernel<<<dim3(1), dim3(256), 0, stream>>>(scales, mode_flag);
  }

  int fast_ok = (ws_size >= NEED && mode_flag) ? 1 : 0;

  if (fast_ok) {
    u16* xh = (u16*)((char*)d_ws + 256);
    u32* wq = (u32*)((char*)d_ws + 256 + XB);
    convert_x_kernel<<<dim3(2048), dim3(256), 0, stream>>>(
        (const float*)x, xh, mode_flag);
    repack_w_kernel<<<dim3(2048), dim3(256), 0, stream>>>(packed, wq);
    q4gemm_fast_kernel<<<dim3(2752), dim3(256), 0, stream>>>(
        xh, wq, (const float*)scales, out, mode_flag);
  }

  q4gemm_slow_kernel<<<dim3(N_DIM / 128, M_DIM / 128), dim3(256), 0, stream>>>(
      x, packed, scales, out, mode_flag, fast_ok);
}

// Round 11
// 925.087 us; speedup vs baseline: 2.2976x; 1.1391x over previous
//
#include <hip/hip_runtime.h>

#define M_DIM 8192
#define N_DIM 11008
#define K_DIM 4096
#define GROUPS 32     // K / 128
#define WQROW 512     // dwords per row of compact W = K/8
#define LDSK 72       // slow kernel pad

typedef short s16x8 __attribute__((ext_vector_type(8)));
typedef _Float16 f16x8 __attribute__((ext_vector_type(8)));
typedef _Float16 h2 __attribute__((ext_vector_type(2)));
typedef float f32x4 __attribute__((ext_vector_type(4)));
typedef unsigned short u16;
typedef unsigned int u32;

union f32u { float f; unsigned u; };
union h16u { u16 u; _Float16 h; };

__device__ __forceinline__ u16 f2bf(float f) {
  f32u v; v.f = f;
  unsigned r = v.u + 0x7FFFu + ((v.u >> 16) & 1u);  // RNE
  return (u16)(r >> 16);
}
__device__ __forceinline__ float bf2f(u16 b) {
  f32u v; v.u = ((unsigned)b) << 16; return v.f;
}
__device__ __forceinline__ float h2f(u16 b) {
  h16u v; v.u = b; return (float)v.h;
}

// ---------------------------------------------------------------------------
// Probe (R3/R4 empirics: harness promotes fp16 -> f32 => mode 0).
// ---------------------------------------------------------------------------
__global__ void probe_mode_kernel(const void* __restrict__ scales,
                                  int* __restrict__ mode_out) {
  __shared__ int cnt[3];
  int t = threadIdx.x;
  if (t < 3) cnt[t] = 0;
  __syncthreads();
  float f0 = ((const float*)scales)[t];
  u16  hu  = ((const u16*)scales)[t];
  float f1 = h2f(hu);
  float f2 = bf2f(hu);
  if (f0 > 0.0004f && f0 < 0.065f) atomicAdd(&cnt[0], 1);
  if (f1 > 0.0004f && f1 < 0.065f) atomicAdd(&cnt[1], 1);
  if (f2 > 0.0004f && f2 < 0.065f) atomicAdd(&cnt[2], 1);
  __syncthreads();
  if (t == 0) {
    int m;
    if      (cnt[1] >= 240) m = 1;
    else if (cnt[2] >= 240) m = 2;
    else                    m = 0;
    mode_out[0] = m;
  }
}

// ---------------------------------------------------------------------------
// BIG-PATH pre-pass 1: x f32 -> fp16, NATURAL order (exact).
// ---------------------------------------------------------------------------
__global__ __launch_bounds__(256) void convert_x_nat_kernel(
    const float* __restrict__ xf, u16* __restrict__ xh,
    const int* __restrict__ modep) {
  if (modep && modep[0] != 0) return;
  const int total8 = M_DIM * (K_DIM / 8);
  int idx = blockIdx.x * 256 + threadIdx.x;
  const int stride = gridDim.x * 256;
  for (; idx < total8; idx += stride) {
    const float4* p = (const float4*)(xf + (size_t)idx * 8);
    float4 a = p[0], b = p[1];
    union { _Float16 h[8]; s16x8 v; } r;
    r.h[0] = (_Float16)a.x; r.h[1] = (_Float16)a.y;
    r.h[2] = (_Float16)a.z; r.h[3] = (_Float16)a.w;
    r.h[4] = (_Float16)b.x; r.h[5] = (_Float16)b.y;
    r.h[6] = (_Float16)b.z; r.h[7] = (_Float16)b.w;
    *(s16x8*)(xh + (size_t)idx * 8) = r.v;
  }
}

// ---------------------------------------------------------------------------
// BIG-PATH pre-pass 2: full dequant W -> fp16 [N][K], natural order.
// One idx = 8 weights = 4 packed int32 (1 payload byte each).
// w = fp16( (nib-8) * s )  — exact product in f32, single rounding: identical
// to the verified in-register dq8 path.
// ---------------------------------------------------------------------------
__global__ __launch_bounds__(256) void dequant_w_kernel(
    const int* __restrict__ packed, const float* __restrict__ scf,
    u16* __restrict__ wf, const int* __restrict__ modep) {
  if (modep && modep[0] != 0) return;
  const int total = N_DIM * (K_DIM / 8);    // 5,636,096 chunks
  int idx = blockIdx.x * 256 + threadIdx.x;
  const int stride = gridDim.x * 256;
  for (; idx < total; idx += stride) {
    const int col = idx >> 9;               // K/8 = 512 chunks per row
    const int d   = idx & 511;
    const float s = scf[col * GROUPS + (d >> 4)];   // group = (d*8)/128
    const int4 p  = ((const int4*)packed)[idx];
    const int vals[4] = {p.x, p.y, p.z, p.w};
    union { _Float16 h[8]; s16x8 v; } r;
    #pragma unroll
    for (int e = 0; e < 4; ++e) {
      int b = vals[e] & 255;
      r.h[2 * e]     = (_Float16)((float)((b & 15) - 8) * s);
      r.h[2 * e + 1] = (_Float16)((float)(((b >> 4) & 15) - 8) * s);
    }
    *(s16x8*)(wf + (size_t)idx * 8) = r.v;
  }
}

// ---------------------------------------------------------------------------
// BIG-PATH GEMM: pure fp16, BM=128, BN=256, BK=64; 4 waves 1x4 in n, acc 8x4.
// R10-verified pipeline: 3 LDS bufs, STAGE 2 ahead, uniform s_waitcnt
// vmcnt(12) + s_barrier per phase (each phase issues exactly 12 VMEM ops:
// STAGE 4 + B 8, so STAGE(T) from phase T-2 has >=12 newer ops under any
// intra-phase reordering). Tail phase issues 0 -> one-time vmcnt(0).
// B: one 16B fp16 fragment load per (j,kkc) — NO dequant in the loop.
// ---------------------------------------------------------------------------
__global__ __launch_bounds__(256, 2) void q4gemm_big_kernel(
    const u16* __restrict__ xh,      // fp16 natural
    const u16* __restrict__ wf,      // fp16 W [N][K]
    float* __restrict__ out,
    const int* __restrict__ modep)
{
  if (modep && modep[0] != 0) return;

  __shared__ _Float16 As[3][128 * 64];   // 48 KiB

  const int tid  = threadIdx.x;
  const int lane = tid & 63;
  const int wv   = tid >> 6;             // 0..3
  const int wn   = wv * 64;
  const int ln15 = lane & 15;
  const int lk   = lane >> 4;            // 0..3

  // XCD swizzle: 2752 = 8 * 344; bm-fastest -> same-XCD neighbors share the
  // 2MB fp16 B panel in L2.
  int bid = blockIdx.x;
  int f   = (bid & 7) * 344 + (bid >> 3);
  int bn  = f / 64;
  int bm  = f - bn * 64;
  const int m0 = bm * 128;
  const int n0 = bn * 256;

  // A staging: LDS[row][slot] = G[row][slot ^ (row&7)] (16B chunks)
  const u16* abase[4];
  #pragma unroll
  for (int q = 0; q < 4; ++q) {
    int row = q * 32 + wv * 8 + (lane >> 3);
    abase[q] = xh + (size_t)(m0 + row) * K_DIM + (((lane & 7) ^ (lane >> 3)) * 8);
  }

#define STAGE(PB, T) do { \
    _Float16* dst = &As[(PB)][0]; \
    _Pragma("unroll") \
    for (int q = 0; q < 4; ++q) \
      __builtin_amdgcn_global_load_lds( \
          (const __attribute__((address_space(1))) void*)(abase[q] + (T) * 64), \
          (__attribute__((address_space(3))) void*)(dst + q * 2048 + wv * 512), \
          16, 0, 0); \
  } while (0)

  // B fragment pointers: col's row is contiguous in k.
  const u16* pB[4];
  #pragma unroll
  for (int j = 0; j < 4; ++j) {
    int col = n0 + wn + j * 16 + ln15;
    pB[j] = wf + (size_t)col * K_DIM + lk * 8;
  }

#define LOADB(RB, T) do { \
    _Pragma("unroll") \
    for (int j = 0; j < 4; ++j) { \
      RB[j]     = *(const f16x8*)(pB[j] + (T) * 64); \
      RB[j + 4] = *(const f16x8*)(pB[j] + (T) * 64 + 32); \
    } \
  } while (0)

#define COMPUTE(RB, PB) do { \
    const _Float16* asb = &As[(PB)][0]; \
    _Pragma("unroll") \
    for (int kkc = 0; kkc < 2; ++kkc) { \
      _Pragma("unroll") \
      for (int i = 0; i < 8; ++i) { \
        const int row  = i * 16 + ln15; \
        const int slot = (kkc * 4 + lk) ^ (ln15 & 7); \
        f16x8 af = *(const f16x8*)&asb[row * 64 + slot * 8]; \
        acc[i][0] = __builtin_amdgcn_mfma_f32_16x16x32_f16(af, RB[kkc * 4 + 0], acc[i][0], 0, 0, 0); \
        acc[i][1] = __builtin_amdgcn_mfma_f32_16x16x32_f16(af, RB[kkc * 4 + 1], acc[i][1], 0, 0, 0); \
        acc[i][2] = __builtin_amdgcn_mfma_f32_16x16x32_f16(af, RB[kkc * 4 + 2], acc[i][2], 0, 0, 0); \
        acc[i][3] = __builtin_amdgcn_mfma_f32_16x16x32_f16(af, RB[kkc * 4 + 3], acc[i][3], 0, 0, 0); \
      } \
    } \
  } while (0)

  f32x4 acc[8][4];
  #pragma unroll
  for (int i = 0; i < 8; ++i)
    #pragma unroll
    for (int j = 0; j < 4; ++j)
      acc[i][j] = f32x4{0.f, 0.f, 0.f, 0.f};

  f16x8 rbE[8], rbO[8];

  // prologue: stage tiles 0,1; B(0),B(1); full drain once.
  STAGE(0, 0);
  STAGE(1, 1);
  LOADB(rbE, 0);
  LOADB(rbO, 1);
  asm volatile("s_waitcnt vmcnt(0)" ::: "memory");

  int p0 = 0, p1 = 1, p2 = 2;

  for (int tp = 0; tp < 32; ++tp) {
    const int t0 = 2 * tp;
    const int t1 = t0 + 1;

    // even phase: tile t0, buf p0, rbE
    asm volatile("s_waitcnt vmcnt(12)" ::: "memory");
    __builtin_amdgcn_s_barrier();
    __builtin_amdgcn_sched_barrier(0);

    if (t0 + 2 < 64) STAGE(p2, t0 + 2);

    __builtin_amdgcn_s_setprio(1);
    COMPUTE(rbE, p0);
    __builtin_amdgcn_s_setprio(0);

    if (t0 + 2 < 64) LOADB(rbE, t0 + 2);

    // odd phase: tile t1, buf p1, rbO
    if (tp == 31) {
      asm volatile("s_waitcnt vmcnt(0)" ::: "memory");   // prev phase issued 0
    } else {
      asm volatile("s_waitcnt vmcnt(12)" ::: "memory");
    }
    __builtin_amdgcn_s_barrier();
    __builtin_amdgcn_sched_barrier(0);

    if (t1 + 2 < 64) STAGE(p0, t1 + 2);

    __builtin_amdgcn_s_setprio(1);
    COMPUTE(rbO, p1);
    __builtin_amdgcn_s_setprio(0);

    if (t1 + 2 < 64) LOADB(rbO, t1 + 2);

    int tmp = p2; p2 = p1; p1 = p0; p0 = tmp;
  }

  // epilogue: C/D col=lane&15, row=(lane>>4)*4+reg
  #pragma unroll
  for (int i = 0; i < 8; ++i) {
    int r0 = m0 + i * 16 + (lane >> 4) * 4;
    #pragma unroll
    for (int j = 0; j < 4; ++j) {
      int cc = n0 + wn + j * 16 + ln15;
      #pragma unroll
      for (int r = 0; r < 4; ++r)
        out[(size_t)(r0 + r) * N_DIM + cc] = acc[i][j][r];
    }
  }
#undef STAGE
#undef LOADB
#undef COMPUTE
}

// ---------------------------------------------------------------------------
// MID PATH (R10 verified, used when ws fits 90MB but not 157MB):
// permuted x convert + compact wq + fused in-register dequant GEMM.
// ---------------------------------------------------------------------------
__global__ __launch_bounds__(256) void convert_x_perm_kernel(
    const float* __restrict__ xf, u16* __restrict__ xh,
    const int* __restrict__ modep) {
  if (modep && modep[0] != 0) return;
  const int total8 = M_DIM * (K_DIM / 8);
  int idx = blockIdx.x * 256 + threadIdx.x;
  const int stride = gridDim.x * 256;
  for (; idx < total8; idx += stride) {
    const float4* p = (const float4*)(xf + (size_t)idx * 8);
    float4 a = p[0], b = p[1];
    union { _Float16 h[8]; s16x8 v; } r;
    r.h[0] = (_Float16)a.x; r.h[1] = (_Float16)b.x;
    r.h[2] = (_Float16)a.y; r.h[3] = (_Float16)b.y;
    r.h[4] = (_Float16)a.z; r.h[5] = (_Float16)b.z;
    r.h[6] = (_Float16)a.w; r.h[7] = (_Float16)b.w;
    *(s16x8*)(xh + (size_t)idx * 8) = r.v;
  }
}

__global__ __launch_bounds__(256) void repack_w_kernel(
    const int* __restrict__ packed, u32* __restrict__ wq) {
  const int total = N_DIM * WQROW;
  int idx = blockIdx.x * 256 + threadIdx.x;
  const int stride = gridDim.x * 256;
  for (; idx < total; idx += stride) {
    const int4 p = ((const int4*)packed)[idx];
    wq[idx] = (u32)(p.x & 255) | ((u32)(p.y & 255) << 8) |
              ((u32)(p.z & 255) << 16) | ((u32)p.w << 24);
  }
}

__device__ __forceinline__ f16x8 dq8(u32 q, h2 s2) {
  const u32 M = 0x000F000Fu, G = 0x64006400u;
  const h2 bias = {(_Float16)(-1032.0f), (_Float16)(-1032.0f)};
  union { u32 u; h2 h; } a0, a1, a2, a3;
  a0.u = (q & M) | G;
  a1.u = ((q >> 4) & M) | G;
  a2.u = ((q >> 8) & M) | G;
  a3.u = ((q >> 12) & M) | G;
  a0.h = (a0.h + bias) * s2;
  a1.h = (a1.h + bias) * s2;
  a2.h = (a2.h + bias) * s2;
  a3.h = (a3.h + bias) * s2;
  union { u32 u[4]; f16x8 f; } r;
  r.u[0] = a0.u; r.u[1] = a1.u; r.u[2] = a2.u; r.u[3] = a3.u;
  return r.f;
}

__global__ __launch_bounds__(256, 2) void q4gemm_mid_kernel(
    const u16* __restrict__ xh, const u32* __restrict__ wq,
    const float* __restrict__ scf, float* __restrict__ out,
    const int* __restrict__ modep)
{
  if (modep && modep[0] != 0) return;

  __shared__ _Float16 As[3][128 * 64];

  const int tid  = threadIdx.x;
  const int lane = tid & 63;
  const int wv   = tid >> 6;
  const int wn   = wv * 64;
  const int ln15 = lane & 15;
  const int lk   = lane >> 4;

  int bid = blockIdx.x;
  int f   = (bid & 7) * 344 + (bid >> 3);
  int bn  = f / 64;
  int bm  = f - bn * 64;
  const int m0 = bm * 128;
  const int n0 = bn * 256;

  const u16* abase[4];
  #pragma unroll
  for (int q = 0; q < 4; ++q) {
    int row = q * 32 + wv * 8 + (lane >> 3);
    abase[q] = xh + (size_t)(m0 + row) * K_DIM + (((lane & 7) ^ (lane >> 3)) * 8);
  }

#define STAGE(PB, T) do { \
    _Float16* dst = &As[(PB)][0]; \
    _Pragma("unroll") \
    for (int q = 0; q < 4; ++q) \
      __builtin_amdgcn_global_load_lds( \
          (const __attribute__((address_space(1))) void*)(abase[q] + (T) * 64), \
          (__attribute__((address_space(3))) void*)(dst + q * 2048 + wv * 512), \
          16, 0, 0); \
  } while (0)

#define LOADB(RB, T) do { \
    _Pragma("unroll") \
    for (int j = 0; j < 4; ++j) { \
      RB[j]     = wq[pcol[j] + (T) * 8]; \
      RB[j + 4] = wq[pcol[j] + (T) * 8 + 4]; \
    } \
  } while (0)

#define COMPUTE(RB, PB) do { \
    const _Float16* asb = &As[(PB)][0]; \
    _Pragma("unroll") \
    for (int kkc = 0; kkc < 2; ++kkc) { \
      f16x8 bfr0 = dq8(RB[kkc * 4 + 0], s2[0]); \
      f16x8 bfr1 = dq8(RB[kkc * 4 + 1], s2[1]); \
      f16x8 bfr2 = dq8(RB[kkc * 4 + 2], s2[2]); \
      f16x8 bfr3 = dq8(RB[kkc * 4 + 3], s2[3]); \
      _Pragma("unroll") \
      for (int i = 0; i < 8; ++i) { \
        const int row  = i * 16 + ln15; \
        const int slot = (kkc * 4 + lk) ^ (ln15 & 7); \
        f16x8 af = *(const f16x8*)&asb[row * 64 + slot * 8]; \
        acc[i][0] = __builtin_amdgcn_mfma_f32_16x16x32_f16(af, bfr0, acc[i][0], 0, 0, 0); \
        acc[i][1] = __builtin_amdgcn_mfma_f32_16x16x32_f16(af, bfr1, acc[i][1], 0, 0, 0); \
        acc[i][2] = __builtin_amdgcn_mfma_f32_16x16x32_f16(af, bfr2, acc[i][2], 0, 0, 0); \
        acc[i][3] = __builtin_amdgcn_mfma_f32_16x16x32_f16(af, bfr3, acc[i][3], 0, 0, 0); \
      } \
    } \
  } while (0)

  int pcol[4], scol[4];
  #pragma unroll
  for (int j = 0; j < 4; ++j) {
    int col = n0 + wn + j * 16 + ln15;
    pcol[j] = col * WQROW + lk;
    scol[j] = col * GROUPS;
  }

  f32x4 acc[8][4];
  #pragma unroll
  for (int i = 0; i < 8; ++i)
    #pragma unroll
    for (int j = 0; j < 4; ++j)
      acc[i][j] = f32x4{0.f, 0.f, 0.f, 0.f};

  u32 rbE[8], rbO[8];
  float snextf[4];
  h2 s2[4];

  STAGE(0, 0);
  STAGE(1, 1);
  LOADB(rbE, 0);
  LOADB(rbO, 1);
  #pragma unroll
  for (int j = 0; j < 4; ++j) snextf[j] = scf[scol[j]];
  asm volatile("s_waitcnt vmcnt(0)" ::: "memory");

  int p0 = 0, p1 = 1, p2 = 2;

  for (int tp = 0; tp < 32; ++tp) {
    const int t0 = 2 * tp;
    const int t1 = t0 + 1;

    asm volatile("s_waitcnt vmcnt(12)" ::: "memory");
    __builtin_amdgcn_s_barrier();
    __builtin_amdgcn_sched_barrier(0);

    #pragma unroll
    for (int j = 0; j < 4; ++j) {
      _Float16 sh = (_Float16)snextf[j];
      s2[j] = h2{sh, sh};
    }
    if (t0 + 2 < 64) STAGE(p2, t0 + 2);

    __builtin_amdgcn_s_setprio(1);
    COMPUTE(rbE, p0);
    __builtin_amdgcn_s_setprio(0);

    if (t0 + 2 < 64) LOADB(rbE, t0 + 2);
    {
      const int gn = (tp + 1 > 31) ? 31 : (tp + 1);
      #pragma unroll
      for (int j = 0; j < 4; ++j) snextf[j] = scf[scol[j] + gn];
    }

    if (tp == 31) {
      asm volatile("s_waitcnt vmcnt(0)" ::: "memory");
    } else {
      asm volatile("s_waitcnt vmcnt(12)" ::: "memory");
    }
    __builtin_amdgcn_s_barrier();
    __builtin_amdgcn_sched_barrier(0);

    if (t1 + 2 < 64) STAGE(p0, t1 + 2);

    __builtin_amdgcn_s_setprio(1);
    COMPUTE(rbO, p1);
    __builtin_amdgcn_s_setprio(0);

    if (t1 + 2 < 64) LOADB(rbO, t1 + 2);

    int tmp = p2; p2 = p1; p1 = p0; p0 = tmp;
  }

  #pragma unroll
  for (int i = 0; i < 8; ++i) {
    int r0 = m0 + i * 16 + (lane >> 4) * 4;
    #pragma unroll
    for (int j = 0; j < 4; ++j) {
      int cc = n0 + wn + j * 16 + ln15;
      #pragma unroll
      for (int r = 0; r < 4; ++r)
        out[(size_t)(r0 + r) * N_DIM + cc] = acc[i][j][r];
    }
  }
#undef STAGE
#undef LOADB
#undef COMPUTE
}

// ---------------------------------------------------------------------------
// SLOW FALLBACK (any mode; skips mode 0 when a fast path ran).
// ---------------------------------------------------------------------------
__global__ __launch_bounds__(256) void q4gemm_slow_kernel(
    const void* __restrict__ xraw,
    const int*  __restrict__ packed,
    const void* __restrict__ scraw,
    float* __restrict__ out,
    const int* __restrict__ modep,
    int skip0)
{
  const int mode = modep ? modep[0] : 0;
  if (skip0 && mode == 0) return;

  __shared__ u16 Asl[128 * LDSK];
  __shared__ u16 Bsl[128 * LDSK];

  const int tid  = threadIdx.x;
  const int lane = tid & 63;
  const int wv   = tid >> 6;
  const int wm   = (wv >> 1) * 64;
  const int wn   = (wv & 1) * 64;
  const int n0   = blockIdx.x * 128;
  const int m0   = blockIdx.y * 128;

  f32x4 acc[4][4];
  #pragma unroll
  for (int i = 0; i < 4; ++i)
    #pragma unroll
    for (int j = 0; j < 4; ++j)
      acc[i][j] = f32x4{0.f, 0.f, 0.f, 0.f};

  const int lrow16 = lane & 15;
  const int lk8    = (lane >> 4) * 8;

  for (int k0 = 0; k0 < K_DIM; k0 += 64) {
    if (mode == 0) {
      const float* xf = (const float*)xraw;
      #pragma unroll
      for (int it = 0; it < 4; ++it) {
        int s = tid + it * 256;
        int row = s >> 3, c8 = (s & 7) * 8;
        const float4* p = (const float4*)(xf + (size_t)(m0 + row) * K_DIM + k0 + c8);
        float4 v0 = p[0], v1 = p[1];
        u16 tmp[8] = { f2bf(v0.x), f2bf(v0.y), f2bf(v0.z), f2bf(v0.w),
                       f2bf(v1.x), f2bf(v1.y), f2bf(v1.z), f2bf(v1.w) };
        *(s16x8*)&Asl[row * LDSK + c8] = *(const s16x8*)tmp;
      }
    } else if (mode == 1) {
      const u16* xhh = (const u16*)xraw;
      #pragma unroll
      for (int it = 0; it < 4; ++it) {
        int s = tid + it * 256;
        int row = s >> 3, c8 = (s & 7) * 8;
        s16x8 v = *(const s16x8*)(xhh + (size_t)(m0 + row) * K_DIM + k0 + c8);
        u16 tmp[8];
        #pragma unroll
        for (int j = 0; j < 8; ++j) tmp[j] = f2bf(h2f((u16)v[j]));
        *(s16x8*)&Asl[row * LDSK + c8] = *(const s16x8*)tmp;
      }
    } else {
      const u16* xhh = (const u16*)xraw;
      #pragma unroll
      for (int it = 0; it < 4; ++it) {
        int s = tid + it * 256;
        int row = s >> 3, c8 = (s & 7) * 8;
        s16x8 v = *(const s16x8*)(xhh + (size_t)(m0 + row) * K_DIM + k0 + c8);
        *(s16x8*)&Asl[row * LDSK + c8] = v;
      }
    }

    {
      int row  = tid >> 1;
      int half = tid & 1;
      int srw  = n0 + row;
      int g    = k0 >> 7;
      float scale;
      if      (mode == 0) scale = ((const float*)scraw)[(size_t)srw * GROUPS + g];
      else if (mode == 1) scale = h2f(((const u16*)scraw)[(size_t)srw * GROUPS + g]);
      else                scale = bf2f(((const u16*)scraw)[(size_t)srw * GROUPS + g]);

      const int4* pp = (const int4*)(packed + (size_t)srw * (K_DIM / 2) + (k0 >> 1) + half * 16);
      #pragma unroll
      for (int j = 0; j < 4; ++j) {
        int4 pv = pp[j];
        int vals[4] = {pv.x, pv.y, pv.z, pv.w};
        u16 w[8];
        #pragma unroll
        for (int e = 0; e < 4; ++e) {
          int b = vals[e] & 255;
          w[e * 2]     = f2bf(scale * (float)((b & 15) - 8));
          w[e * 2 + 1] = f2bf(scale * (float)(((b >> 4) & 15) - 8));
        }
        int i0 = half * 16 + j * 4;
        *(s16x8*)&Bsl[row * LDSK + i0 * 2] = *(const s16x8*)w;
      }
    }
    __syncthreads();

    #pragma unroll
    for (int kk = 0; kk < 64; kk += 32) {
      s16x8 af[4], bfr[4];
      int klane = kk + lk8;
      #pragma unroll
      for (int i = 0; i < 4; ++i)
        af[i] = *(const s16x8*)&Asl[(wm + i * 16 + lrow16) * LDSK + klane];
      #pragma unroll
      for (int i = 0; i < 4; ++i)
        bfr[i] = *(const s16x8*)&Bsl[(wn + i * 16 + lrow16) * LDSK + klane];
      #pragma unroll
      for (int i = 0; i < 4; ++i)
        #pragma unroll
        for (int j = 0; j < 4; ++j)
          acc[i][j] = __builtin_amdgcn_mfma_f32_16x16x32_bf16(af[i], bfr[j], acc[i][j], 0, 0, 0);
    }
    __syncthreads();
  }

  #pragma unroll
  for (int i = 0; i < 4; ++i) {
    int rbase = m0 + wm + i * 16 + ((lane >> 4) * 4);
    #pragma unroll
    for (int j = 0; j < 4; ++j) {
      int c = n0 + wn + j * 16 + (lane & 15);
      #pragma unroll
      for (int r = 0; r < 4; ++r)
        out[(size_t)(rbase + r) * N_DIM + c] = acc[i][j][r];
    }
  }
}

extern "C" void kernel_launch(void* const* d_in, const int* in_sizes, int n_in,
                              void* d_out, int out_size, void* d_ws, size_t ws_size,
                              hipStream_t stream) {
  const void* x      = d_in[0];
  const int*  packed = (const int*)d_in[1];
  const void* scales = d_in[2];
  float* out = (float*)d_out;

  const size_t XB = (size_t)M_DIM * K_DIM * 2;        // 67,108,864 B
  const size_t WF = (size_t)N_DIM * K_DIM * 2;        // 90,177,536 B
  const size_t WQ = (size_t)N_DIM * WQROW * 4;        // 22,544,384 B
  const size_t NEED_BIG = 256 + XB + WF;              // ~157.3 MB
  const size_t NEED_MID = 256 + XB + WQ;              // ~89.7 MB

  int* mode_flag = nullptr;
  if (ws_size >= 4) {
    mode_flag = (int*)d_ws;
    probe_mode_kernel<<<dim3(1), dim3(256), 0, stream>>>(scales, mode_flag);
  }

  int fast = 0;
  if (mode_flag && ws_size >= NEED_BIG) fast = 2;
  else if (mode_flag && ws_size >= NEED_MID) fast = 1;

  if (fast == 2) {
    u16* xh = (u16*)((char*)d_ws + 256);
    u16* wf = (u16*)((char*)d_ws + 256 + XB);
    convert_x_nat_kernel<<<dim3(2048), dim3(256), 0, stream>>>(
        (const float*)x, xh, mode_flag);
    dequant_w_kernel<<<dim3(2048), dim3(256), 0, stream>>>(
        packed, (const float*)scales, wf, mode_flag);
    q4gemm_big_kernel<<<dim3(2752), dim3(256), 0, stream>>>(
        xh, wf, out, mode_flag);
  } else if (fast == 1) {
    u16* xh = (u16*)((char*)d_ws + 256);
    u32* wq = (u32*)((char*)d_ws + 256 + XB);
    convert_x_perm_kernel<<<dim3(2048), dim3(256), 0, stream>>>(
        (const float*)x, xh, mode_flag);
    repack_w_kernel<<<dim3(2048), dim3(256), 0, stream>>>(packed, wq);
    q4gemm_mid_kernel<<<dim3(2752), dim3(256), 0, stream>>>(
        xh, wq, (const float*)scales, out, mode_flag);
  }

  q4gemm_slow_kernel<<<dim3(N_DIM / 128, M_DIM / 128), dim3(256), 0, stream>>>(
      x, packed, scales, out, mode_flag, fast);
}

// Round 12
// 924.045 us; speedup vs baseline: 2.3002x; 1.0011x over previous
//
#include <hip/hip_runtime.h>

#define M_DIM 8192
#define N_DIM 11008
#define K_DIM 4096
#define GROUPS 32     // K / 128
#define WQROW 512     // dwords per row of compact W = K/8
#define LDSK 72       // slow kernel pad

typedef short s16x8 __attribute__((ext_vector_type(8)));
typedef _Float16 f16x8 __attribute__((ext_vector_type(8)));
typedef _Float16 h2 __attribute__((ext_vector_type(2)));
typedef float f32x4 __attribute__((ext_vector_type(4)));
typedef unsigned short u16;
typedef unsigned int u32;

union f32u { float f; unsigned u; };
union h16u { u16 u; _Float16 h; };

__device__ __forceinline__ u16 f2bf(float f) {
  f32u v; v.f = f;
  unsigned r = v.u + 0x7FFFu + ((v.u >> 16) & 1u);  // RNE
  return (u16)(r >> 16);
}
__device__ __forceinline__ float bf2f(u16 b) {
  f32u v; v.u = ((unsigned)b) << 16; return v.f;
}
__device__ __forceinline__ float h2f(u16 b) {
  h16u v; v.u = b; return (float)v.h;
}

// ---------------------------------------------------------------------------
// Probe (R3/R4 empirics: harness promotes fp16 -> f32 => mode 0).
// ---------------------------------------------------------------------------
__global__ void probe_mode_kernel(const void* __restrict__ scales,
                                  int* __restrict__ mode_out) {
  __shared__ int cnt[3];
  int t = threadIdx.x;
  if (t < 3) cnt[t] = 0;
  __syncthreads();
  float f0 = ((const float*)scales)[t];
  u16  hu  = ((const u16*)scales)[t];
  float f1 = h2f(hu);
  float f2 = bf2f(hu);
  if (f0 > 0.0004f && f0 < 0.065f) atomicAdd(&cnt[0], 1);
  if (f1 > 0.0004f && f1 < 0.065f) atomicAdd(&cnt[1], 1);
  if (f2 > 0.0004f && f2 < 0.065f) atomicAdd(&cnt[2], 1);
  __syncthreads();
  if (t == 0) {
    int m;
    if      (cnt[1] >= 240) m = 1;
    else if (cnt[2] >= 240) m = 2;
    else                    m = 0;
    mode_out[0] = m;
  }
}

// ---------------------------------------------------------------------------
// BIG-PATH pre-pass 1: x f32 -> fp16, NATURAL order (exact).
// ---------------------------------------------------------------------------
__global__ __launch_bounds__(256) void convert_x_nat_kernel(
    const float* __restrict__ xf, u16* __restrict__ xh,
    const int* __restrict__ modep) {
  if (modep && modep[0] != 0) return;
  const int total8 = M_DIM * (K_DIM / 8);
  int idx = blockIdx.x * 256 + threadIdx.x;
  const int stride = gridDim.x * 256;
  for (; idx < total8; idx += stride) {
    const float4* p = (const float4*)(xf + (size_t)idx * 8);
    float4 a = p[0], b = p[1];
    union { _Float16 h[8]; s16x8 v; } r;
    r.h[0] = (_Float16)a.x; r.h[1] = (_Float16)a.y;
    r.h[2] = (_Float16)a.z; r.h[3] = (_Float16)a.w;
    r.h[4] = (_Float16)b.x; r.h[5] = (_Float16)b.y;
    r.h[6] = (_Float16)b.z; r.h[7] = (_Float16)b.w;
    *(s16x8*)(xh + (size_t)idx * 8) = r.v;
  }
}

// ---------------------------------------------------------------------------
// BIG-PATH pre-pass 2: full dequant W -> fp16 [N][K], natural order.
// One idx = 8 weights = 4 packed int32 (1 payload byte each).
// w = fp16( (nib-8) * s )  — exact product in f32, single rounding: identical
// to the verified in-register dq8 path.
// ---------------------------------------------------------------------------
__global__ __launch_bounds__(256) void dequant_w_kernel(
    const int* __restrict__ packed, const float* __restrict__ scf,
    u16* __restrict__ wf, const int* __restrict__ modep) {
  if (modep && modep[0] != 0) return;
  const int total = N_DIM * (K_DIM / 8);    // 5,636,096 chunks
  int idx = blockIdx.x * 256 + threadIdx.x;
  const int stride = gridDim.x * 256;
  for (; idx < total; idx += stride) {
    const int col = idx >> 9;               // K/8 = 512 chunks per row
    const int d   = idx & 511;
    const float s = scf[col * GROUPS + (d >> 4)];   // group = (d*8)/128
    const int4 p  = ((const int4*)packed)[idx];
    const int vals[4] = {p.x, p.y, p.z, p.w};
    union { _Float16 h[8]; s16x8 v; } r;
    #pragma unroll
    for (int e = 0; e < 4; ++e) {
      int b = vals[e] & 255;
      r.h[2 * e]     = (_Float16)((float)((b & 15) - 8) * s);
      r.h[2 * e + 1] = (_Float16)((float)(((b >> 4) & 15) - 8) * s);
    }
    *(s16x8*)(wf + (size_t)idx * 8) = r.v;
  }
}

// ---------------------------------------------------------------------------
// BIG-PATH GEMM: pure fp16, BM=128, BN=256, BK=64; 4 waves 1x4 in n, acc 8x4.
// R10-verified pipeline: 3 LDS bufs, STAGE 2 ahead, uniform s_waitcnt
// vmcnt(12) + s_barrier per phase (each phase issues exactly 12 VMEM ops:
// STAGE 4 + B 8, so STAGE(T) from phase T-2 has >=12 newer ops under any
// intra-phase reordering). Tail phase issues 0 -> one-time vmcnt(0).
// B: one 16B fp16 fragment load per (j,kkc) — NO dequant in the loop.
// ---------------------------------------------------------------------------
__global__ __launch_bounds__(256, 2) void q4gemm_big_kernel(
    const u16* __restrict__ xh,      // fp16 natural
    const u16* __restrict__ wf,      // fp16 W [N][K]
    float* __restrict__ out,
    const int* __restrict__ modep)
{
  if (modep && modep[0] != 0) return;

  __shared__ _Float16 As[3][128 * 64];   // 48 KiB

  const int tid  = threadIdx.x;
  const int lane = tid & 63;
  const int wv   = tid >> 6;             // 0..3
  const int wn   = wv * 64;
  const int ln15 = lane & 15;
  const int lk   = lane >> 4;            // 0..3

  // XCD swizzle: 2752 = 8 * 344; bm-fastest -> same-XCD neighbors share the
  // 2MB fp16 B panel in L2.
  int bid = blockIdx.x;
  int f   = (bid & 7) * 344 + (bid >> 3);
  int bn  = f / 64;
  int bm  = f - bn * 64;
  const int m0 = bm * 128;
  const int n0 = bn * 256;

  // A staging: LDS[row][slot] = G[row][slot ^ (row&7)] (16B chunks)
  const u16* abase[4];
  #pragma unroll
  for (int q = 0; q < 4; ++q) {
    int row = q * 32 + wv * 8 + (lane >> 3);
    abase[q] = xh + (size_t)(m0 + row) * K_DIM + (((lane & 7) ^ (lane >> 3)) * 8);
  }

#define STAGE(PB, T) do { \
    _Float16* dst = &As[(PB)][0]; \
    _Pragma("unroll") \
    for (int q = 0; q < 4; ++q) \
      __builtin_amdgcn_global_load_lds( \
          (const __attribute__((address_space(1))) void*)(abase[q] + (T) * 64), \
          (__attribute__((address_space(3))) void*)(dst + q * 2048 + wv * 512), \
          16, 0, 0); \
  } while (0)

  // B fragment pointers: col's row is contiguous in k.
  const u16* pB[4];
  #pragma unroll
  for (int j = 0; j < 4; ++j) {
    int col = n0 + wn + j * 16 + ln15;
    pB[j] = wf + (size_t)col * K_DIM + lk * 8;
  }

#define LOADB(RB, T) do { \
    _Pragma("unroll") \
    for (int j = 0; j < 4; ++j) { \
      RB[j]     = *(const f16x8*)(pB[j] + (T) * 64); \
      RB[j + 4] = *(const f16x8*)(pB[j] + (T) * 64 + 32); \
    } \
  } while (0)

#define COMPUTE(RB, PB) do { \
    const _Float16* asb = &As[(PB)][0]; \
    _Pragma("unroll") \
    for (int kkc = 0; kkc < 2; ++kkc) { \
      _Pragma("unroll") \
      for (int i = 0; i < 8; ++i) { \
        const int row  = i * 16 + ln15; \
        const int slot = (kkc * 4 + lk) ^ (ln15 & 7); \
        f16x8 af = *(const f16x8*)&asb[row * 64 + slot * 8]; \
        acc[i][0] = __builtin_amdgcn_mfma_f32_16x16x32_f16(af, RB[kkc * 4 + 0], acc[i][0], 0, 0, 0); \
        acc[i][1] = __builtin_amdgcn_mfma_f32_16x16x32_f16(af, RB[kkc * 4 + 1], acc[i][1], 0, 0, 0); \
        acc[i][2] = __builtin_amdgcn_mfma_f32_16x16x32_f16(af, RB[kkc * 4 + 2], acc[i][2], 0, 0, 0); \
        acc[i][3] = __builtin_amdgcn_mfma_f32_16x16x32_f16(af, RB[kkc * 4 + 3], acc[i][3], 0, 0, 0); \
      } \
    } \
  } while (0)

  f32x4 acc[8][4];
  #pragma unroll
  for (int i = 0; i < 8; ++i)
    #pragma unroll
    for (int j = 0; j < 4; ++j)
      acc[i][j] = f32x4{0.f, 0.f, 0.f, 0.f};

  f16x8 rbE[8], rbO[8];

  // prologue: stage tiles 0,1; B(0),B(1); full drain once.
  STAGE(0, 0);
  STAGE(1, 1);
  LOADB(rbE, 0);
  LOADB(rbO, 1);
  asm volatile("s_waitcnt vmcnt(0)" ::: "memory");

  int p0 = 0, p1 = 1, p2 = 2;

  for (int tp = 0; tp < 32; ++tp) {
    const int t0 = 2 * tp;
    const int t1 = t0 + 1;

    // even phase: tile t0, buf p0, rbE
    asm volatile("s_waitcnt vmcnt(12)" ::: "memory");
    __builtin_amdgcn_s_barrier();
    __builtin_amdgcn_sched_barrier(0);

    if (t0 + 2 < 64) STAGE(p2, t0 + 2);

    __builtin_amdgcn_s_setprio(1);
    COMPUTE(rbE, p0);
    __builtin_amdgcn_s_setprio(0);

    if (t0 + 2 < 64) LOADB(rbE, t0 + 2);

    // odd phase: tile t1, buf p1, rbO
    if (tp == 31) {
      asm volatile("s_waitcnt vmcnt(0)" ::: "memory");   // prev phase issued 0
    } else {
      asm volatile("s_waitcnt vmcnt(12)" ::: "memory");
    }
    __builtin_amdgcn_s_barrier();
    __builtin_amdgcn_sched_barrier(0);

    if (t1 + 2 < 64) STAGE(p0, t1 + 2);

    __builtin_amdgcn_s_setprio(1);
    COMPUTE(rbO, p1);
    __builtin_amdgcn_s_setprio(0);

    if (t1 + 2 < 64) LOADB(rbO, t1 + 2);

    int tmp = p2; p2 = p1; p1 = p0; p0 = tmp;
  }

  // epilogue: C/D col=lane&15, row=(lane>>4)*4+reg
  #pragma unroll
  for (int i = 0; i < 8; ++i) {
    int r0 = m0 + i * 16 + (lane >> 4) * 4;
    #pragma unroll
    for (int j = 0; j < 4; ++j) {
      int cc = n0 + wn + j * 16 + ln15;
      #pragma unroll
      for (int r = 0; r < 4; ++r)
        out[(size_t)(r0 + r) * N_DIM + cc] = acc[i][j][r];
    }
  }
#undef STAGE
#undef LOADB
#undef COMPUTE
}

// ---------------------------------------------------------------------------
// MID PATH (R10 verified, used when ws fits 90MB but not 157MB):
// permuted x convert + compact wq + fused in-register dequant GEMM.
// ---------------------------------------------------------------------------
__global__ __launch_bounds__(256) void convert_x_perm_kernel(
    const float* __restrict__ xf, u16* __restrict__ xh,
    const int* __restrict__ modep) {
  if (modep && modep[0] != 0) return;
  const int total8 = M_DIM * (K_DIM / 8);
  int idx = blockIdx.x * 256 + threadIdx.x;
  const int stride = gridDim.x * 256;
  for (; idx < total8; idx += stride) {
    const float4* p = (const float4*)(xf + (size_t)idx * 8);
    float4 a = p[0], b = p[1];
    union { _Float16 h[8]; s16x8 v; } r;
    r.h[0] = (_Float16)a.x; r.h[1] = (_Float16)b.x;
    r.h[2] = (_Float16)a.y; r.h[3] = (_Float16)b.y;
    r.h[4] = (_Float16)a.z; r.h[5] = (_Float16)b.z;
    r.h[6] = (_Float16)a.w; r.h[7] = (_Float16)b.w;
    *(s16x8*)(xh + (size_t)idx * 8) = r.v;
  }
}

__global__ __launch_bounds__(256) void repack_w_kernel(
    const int* __restrict__ packed, u32* __restrict__ wq) {
  const int total = N_DIM * WQROW;
  int idx = blockIdx.x * 256 + threadIdx.x;
  const int stride = gridDim.x * 256;
  for (; idx < total; idx += stride) {
    const int4 p = ((const int4*)packed)[idx];
    wq[idx] = (u32)(p.x & 255) | ((u32)(p.y & 255) << 8) |
              ((u32)(p.z & 255) << 16) | ((u32)p.w << 24);
  }
}

__device__ __forceinline__ f16x8 dq8(u32 q, h2 s2) {
  const u32 M = 0x000F000Fu, G = 0x64006400u;
  const h2 bias = {(_Float16)(-1032.0f), (_Float16)(-1032.0f)};
  union { u32 u; h2 h; } a0, a1, a2, a3;
  a0.u = (q & M) | G;
  a1.u = ((q >> 4) & M) | G;
  a2.u = ((q >> 8) & M) | G;
  a3.u = ((q >> 12) & M) | G;
  a0.h = (a0.h + bias) * s2;
  a1.h = (a1.h + bias) * s2;
  a2.h = (a2.h + bias) * s2;
  a3.h = (a3.h + bias) * s2;
  union { u32 u[4]; f16x8 f; } r;
  r.u[0] = a0.u; r.u[1] = a1.u; r.u[2] = a2.u; r.u[3] = a3.u;
  return r.f;
}

__global__ __launch_bounds__(256, 2) void q4gemm_mid_kernel(
    const u16* __restrict__ xh, const u32* __restrict__ wq,
    const float* __restrict__ scf, float* __restrict__ out,
    const int* __restrict__ modep)
{
  if (modep && modep[0] != 0) return;

  __shared__ _Float16 As[3][128 * 64];

  const int tid  = threadIdx.x;
  const int lane = tid & 63;
  const int wv   = tid >> 6;
  const int wn   = wv * 64;
  const int ln15 = lane & 15;
  const int lk   = lane >> 4;

  int bid = blockIdx.x;
  int f   = (bid & 7) * 344 + (bid >> 3);
  int bn  = f / 64;
  int bm  = f - bn * 64;
  const int m0 = bm * 128;
  const int n0 = bn * 256;

  const u16* abase[4];
  #pragma unroll
  for (int q = 0; q < 4; ++q) {
    int row = q * 32 + wv * 8 + (lane >> 3);
    abase[q] = xh + (size_t)(m0 + row) * K_DIM + (((lane & 7) ^ (lane >> 3)) * 8);
  }

#define STAGE(PB, T) do { \
    _Float16* dst = &As[(PB)][0]; \
    _Pragma("unroll") \
    for (int q = 0; q < 4; ++q) \
      __builtin_amdgcn_global_load_lds( \
          (const __attribute__((address_space(1))) void*)(abase[q] + (T) * 64), \
          (__attribute__((address_space(3))) void*)(dst + q * 2048 + wv * 512), \
          16, 0, 0); \
  } while (0)

#define LOADB(RB, T) do { \
    _Pragma("unroll") \
    for (int j = 0; j < 4; ++j) { \
      RB[j]     = wq[pcol[j] + (T) * 8]; \
      RB[j + 4] = wq[pcol[j] + (T) * 8 + 4]; \
    } \
  } while (0)

#define COMPUTE(RB, PB) do { \
    const _Float16* asb = &As[(PB)][0]; \
    _Pragma("unroll") \
    for (int kkc = 0; kkc < 2; ++kkc) { \
      f16x8 bfr0 = dq8(RB[kkc * 4 + 0], s2[0]); \
      f16x8 bfr1 = dq8(RB[kkc * 4 + 1], s2[1]); \
      f16x8 bfr2 = dq8(RB[kkc * 4 + 2], s2[2]); \
      f16x8 bfr3 = dq8(RB[kkc * 4 + 3], s2[3]); \
      _Pragma("unroll") \
      for (int i = 0; i < 8; ++i) { \
        const int row  = i * 16 + ln15; \
        const int slot = (kkc * 4 + lk) ^ (ln15 & 7); \
        f16x8 af = *(const f16x8*)&asb[row * 64 + slot * 8]; \
        acc[i][0] = __builtin_amdgcn_mfma_f32_16x16x32_f16(af, bfr0, acc[i][0], 0, 0, 0); \
        acc[i][1] = __builtin_amdgcn_mfma_f32_16x16x32_f16(af, bfr1, acc[i][1], 0, 0, 0); \
        acc[i][2] = __builtin_amdgcn_mfma_f32_16x16x32_f16(af, bfr2, acc[i][2], 0, 0, 0); \
        acc[i][3] = __builtin_amdgcn_mfma_f32_16x16x32_f16(af, bfr3, acc[i][3], 0, 0, 0); \
      } \
    } \
  } while (0)

  int pcol[4], scol[4];
  #pragma unroll
  for (int j = 0; j < 4; ++j) {
    int col = n0 + wn + j * 16 + ln15;
    pcol[j] = col * WQROW + lk;
    scol[j] = col * GROUPS;
  }

  f32x4 acc[8][4];
  #pragma unroll
  for (int i = 0; i < 8; ++i)
    #pragma unroll
    for (int j = 0; j < 4; ++j)
      acc[i][j] = f32x4{0.f, 0.f, 0.f, 0.f};

  u32 rbE[8], rbO[8];
  float snextf[4];
  h2 s2[4];

  STAGE(0, 0);
  STAGE(1, 1);
  LOADB(rbE, 0);
  LOADB(rbO, 1);
  #pragma unroll
  for (int j = 0; j < 4; ++j) snextf[j] = scf[scol[j]];
  asm volatile("s_waitcnt vmcnt(0)" ::: "memory");

  int p0 = 0, p1 = 1, p2 = 2;

  for (int tp = 0; tp < 32; ++tp) {
    const int t0 = 2 * tp;
    const int t1 = t0 + 1;

    asm volatile("s_waitcnt vmcnt(12)" ::: "memory");
    __builtin_amdgcn_s_barrier();
    __builtin_amdgcn_sched_barrier(0);

    #pragma unroll
    for (int j = 0; j < 4; ++j) {
      _Float16 sh = (_Float16)snextf[j];
      s2[j] = h2{sh, sh};
    }
    if (t0 + 2 < 64) STAGE(p2, t0 + 2);

    __builtin_amdgcn_s_setprio(1);
    COMPUTE(rbE, p0);
    __builtin_amdgcn_s_setprio(0);

    if (t0 + 2 < 64) LOADB(rbE, t0 + 2);
    {
      const int gn = (tp + 1 > 31) ? 31 : (tp + 1);
      #pragma unroll
      for (int j = 0; j < 4; ++j) snextf[j] = scf[scol[j] + gn];
    }

    if (tp == 31) {
      asm volatile("s_waitcnt vmcnt(0)" ::: "memory");
    } else {
      asm volatile("s_waitcnt vmcnt(12)" ::: "memory");
    }
    __builtin_amdgcn_s_barrier();
    __builtin_amdgcn_sched_barrier(0);

    if (t1 + 2 < 64) STAGE(p0, t1 + 2);

    __builtin_amdgcn_s_setprio(1);
    COMPUTE(rbO, p1);
    __builtin_amdgcn_s_setprio(0);

    if (t1 + 2 < 64) LOADB(rbO, t1 + 2);

    int tmp = p2; p2 = p1; p1 = p0; p0 = tmp;
  }

  #pragma unroll
  for (int i = 0; i < 8; ++i) {
    int r0 = m0 + i * 16 + (lane >> 4) * 4;
    #pragma unroll
    for (int j = 0; j < 4; ++j) {
      int cc = n0 + wn + j * 16 + ln15;
      #pragma unroll
      for (int r = 0; r < 4; ++r)
        out[(size_t)(r0 + r) * N_DIM + cc] = acc[i][j][r];
    }
  }
#undef STAGE
#undef LOADB
#undef COMPUTE
}

// ---------------------------------------------------------------------------
// SLOW FALLBACK (any mode; skips mode 0 when a fast path ran).
// ---------------------------------------------------------------------------
__global__ __launch_bounds__(256) void q4gemm_slow_kernel(
    const void* __restrict__ xraw,
    const int*  __restrict__ packed,
    const void* __restrict__ scraw,
    float* __restrict__ out,
    const int* __restrict__ modep,
    int skip0)
{
  const int mode = modep ? modep[0] : 0;
  if (skip0 && mode == 0) return;

  __shared__ u16 Asl[128 * LDSK];
  __shared__ u16 Bsl[128 * LDSK];

  const int tid  = threadIdx.x;
  const int lane = tid & 63;
  const int wv   = tid >> 6;
  const int wm   = (wv >> 1) * 64;
  const int wn   = (wv & 1) * 64;
  const int n0   = blockIdx.x * 128;
  const int m0   = blockIdx.y * 128;

  f32x4 acc[4][4];
  #pragma unroll
  for (int i = 0; i < 4; ++i)
    #pragma unroll
    for (int j = 0; j < 4; ++j)
      acc[i][j] = f32x4{0.f, 0.f, 0.f, 0.f};

  const int lrow16 = lane & 15;
  const int lk8    = (lane >> 4) * 8;

  for (int k0 = 0; k0 < K_DIM; k0 += 64) {
    if (mode == 0) {
      const float* xf = (const float*)xraw;
      #pragma unroll
      for (int it = 0; it < 4; ++it) {
        int s = tid + it * 256;
        int row = s >> 3, c8 = (s & 7) * 8;
        const float4* p = (const float4*)(xf + (size_t)(m0 + row) * K_DIM + k0 + c8);
        float4 v0 = p[0], v1 = p[1];
        u16 tmp[8] = { f2bf(v0.x), f2bf(v0.y), f2bf(v0.z), f2bf(v0.w),
                       f2bf(v1.x), f2bf(v1.y), f2bf(v1.z), f2bf(v1.w) };
        *(s16x8*)&Asl[row * LDSK + c8] = *(const s16x8*)tmp;
      }
    } else if (mode == 1) {
      const u16* xhh = (const u16*)xraw;
      #pragma unroll
      for (int it = 0; it < 4; ++it) {
        int s = tid + it * 256;
        int row = s >> 3, c8 = (s & 7) * 8;
        s16x8 v = *(const s16x8*)(xhh + (size_t)(m0 + row) * K_DIM + k0 + c8);
        u16 tmp[8];
        #pragma unroll
        for (int j = 0; j < 8; ++j) tmp[j] = f2bf(h2f((u16)v[j]));
        *(s16x8*)&Asl[row * LDSK + c8] = *(const s16x8*)tmp;
      }
    } else {
      const u16* xhh = (const u16*)xraw;
      #pragma unroll
      for (int it = 0; it < 4; ++it) {
        int s = tid + it * 256;
        int row = s >> 3, c8 = (s & 7) * 8;
        s16x8 v = *(const s16x8*)(xhh + (size_t)(m0 + row) * K_DIM + k0 + c8);
        *(s16x8*)&Asl[row * LDSK + c8] = v;
      }
    }

    {
      int row  = tid >> 1;
      int half = tid & 1;
      int srw  = n0 + row;
      int g    = k0 >> 7;
      float scale;
      if      (mode == 0) scale = ((const float*)scraw)[(size_t)srw * GROUPS + g];
      else if (mode == 1) scale = h2f(((const u16*)scraw)[(size_t)srw * GROUPS + g]);
      else                scale = bf2f(((const u16*)scraw)[(size_t)srw * GROUPS + g]);

      const int4* pp = (const int4*)(packed + (size_t)srw * (K_DIM / 2) + (k0 >> 1) + half * 16);
      #pragma unroll
      for (int j = 0; j < 4; ++j) {
        int4 pv = pp[j];
        int vals[4] = {pv.x, pv.y, pv.z, pv.w};
        u16 w[8];
        #pragma unroll
        for (int e = 0; e < 4; ++e) {
          int b = vals[e] & 255;
          w[e * 2]     = f2bf(scale * (float)((b & 15) - 8));
          w[e * 2 + 1] = f2bf(scale * (float)(((b >> 4) & 15) - 8));
        }
        int i0 = half * 16 + j * 4;
        *(s16x8*)&Bsl[row * LDSK + i0 * 2] = *(const s16x8*)w;
      }
    }
    __syncthreads();

    #pragma unroll
    for (int kk = 0; kk < 64; kk += 32) {
      s16x8 af[4], bfr[4];
      int klane = kk + lk8;
      #pragma unroll
      for (int i = 0; i < 4; ++i)
        af[i] = *(const s16x8*)&Asl[(wm + i * 16 + lrow16) * LDSK + klane];
      #pragma unroll
      for (int i = 0; i < 4; ++i)
        bfr[i] = *(const s16x8*)&Bsl[(wn + i * 16 + lrow16) * LDSK + klane];
      #pragma unroll
      for (int i = 0; i < 4; ++i)
        #pragma unroll
        for (int j = 0; j < 4; ++j)
          acc[i][j] = __builtin_amdgcn_mfma_f32_16x16x32_bf16(af[i], bfr[j], acc[i][j], 0, 0, 0);
    }
    __syncthreads();
  }

  #pragma unroll
  for (int i = 0; i < 4; ++i) {
    int rbase = m0 + wm + i * 16 + ((lane >> 4) * 4);
    #pragma unroll
    for (int j = 0; j < 4; ++j) {
      int c = n0 + wn + j * 16 + (lane & 15);
      #pragma unroll
      for (int r = 0; r < 4; ++r)
        out[(size_t)(rbase + r) * N_DIM + c] = acc[i][j][r];
    }
  }
}

extern "C" void kernel_launch(void* const* d_in, const int* in_sizes, int n_in,
                              void* d_out, int out_size, void* d_ws, size_t ws_size,
                              hipStream_t stream) {
  const void* x      = d_in[0];
  const int*  packed = (const int*)d_in[1];
  const void* scales = d_in[2];
  float* out = (float*)d_out;

  const size_t XB = (size_t)M_DIM * K_DIM * 2;        // 67,108,864 B
  const size_t WF = (size_t)N_DIM * K_DIM * 2;        // 90,177,536 B
  const size_t WQ = (size_t)N_DIM * WQROW * 4;        // 22,544,384 B
  const size_t NEED_BIG = 256 + XB + WF;              // ~157.3 MB
  const size_t NEED_MID = 256 + XB + WQ;              // ~89.7 MB

  int* mode_flag = nullptr;
  if (ws_size >= 4) {
    mode_flag = (int*)d_ws;
    probe_mode_kernel<<<dim3(1), dim3(256), 0, stream>>>(scales, mode_flag);
  }

  int fast = 0;
  if (mode_flag && ws_size >= NEED_BIG) fast = 2;
  else if (mode_flag && ws_size >= NEED_MID) fast = 1;

  if (fast == 2) {
    u16* xh = (u16*)((char*)d_ws + 256);
    u16* wf = (u16*)((char*)d_ws + 256 + XB);
    convert_x_nat_kernel<<<dim3(2048), dim3(256), 0, stream>>>(
        (const float*)x, xh, mode_flag);
    dequant_w_kernel<<<dim3(2048), dim3(256), 0, stream>>>(
        packed, (const float*)scales, wf, mode_flag);
    q4gemm_big_kernel<<<dim3(2752), dim3(256), 0, stream>>>(
        xh, wf, out, mode_flag);
  } else if (fast == 1) {
    u16* xh = (u16*)((char*)d_ws + 256);
    u32* wq = (u32*)((char*)d_ws + 256 + XB);
    convert_x_perm_kernel<<<dim3(2048), dim3(256), 0, stream>>>(
        (const float*)x, xh, mode_flag);
    repack_w_kernel<<<dim3(2048), dim3(256), 0, stream>>>(packed, wq);
    q4gemm_mid_kernel<<<dim3(2752), dim3(256), 0, stream>>>(
        xh, wq, (const float*)scales, out, mode_flag);
  }

  q4gemm_slow_kernel<<<dim3(N_DIM / 128, M_DIM / 128), dim3(256), 0, stream>>>(
      x, packed, scales, out, mode_flag, fast);
}

// Round 13
// 905.588 us; speedup vs baseline: 2.3471x; 1.0204x over previous
//
#include <hip/hip_runtime.h>

#define M_DIM 8192
#define N_DIM 11008
#define K_DIM 4096
#define GROUPS 32     // K / 128
#define WQROW 512     // dwords per row of compact W = K/8
#define LDSK 72       // slow kernel pad

typedef short s16x8 __attribute__((ext_vector_type(8)));
typedef _Float16 f16x8 __attribute__((ext_vector_type(8)));
typedef _Float16 h2 __attribute__((ext_vector_type(2)));
typedef float f32x4 __attribute__((ext_vector_type(4)));
typedef unsigned short u16;
typedef unsigned int u32;

union f32u { float f; unsigned u; };
union h16u { u16 u; _Float16 h; };

__device__ __forceinline__ u16 f2bf(float f) {
  f32u v; v.f = f;
  unsigned r = v.u + 0x7FFFu + ((v.u >> 16) & 1u);  // RNE
  return (u16)(r >> 16);
}
__device__ __forceinline__ float bf2f(u16 b) {
  f32u v; v.u = ((unsigned)b) << 16; return v.f;
}
__device__ __forceinline__ float h2f(u16 b) {
  h16u v; v.u = b; return (float)v.h;
}

// ---------------------------------------------------------------------------
// Probe (R3/R4 empirics: harness promotes fp16 -> f32 => mode 0).
// ---------------------------------------------------------------------------
__global__ void probe_mode_kernel(const void* __restrict__ scales,
                                  int* __restrict__ mode_out) {
  __shared__ int cnt[3];
  int t = threadIdx.x;
  if (t < 3) cnt[t] = 0;
  __syncthreads();
  float f0 = ((const float*)scales)[t];
  u16  hu  = ((const u16*)scales)[t];
  float f1 = h2f(hu);
  float f2 = bf2f(hu);
  if (f0 > 0.0004f && f0 < 0.065f) atomicAdd(&cnt[0], 1);
  if (f1 > 0.0004f && f1 < 0.065f) atomicAdd(&cnt[1], 1);
  if (f2 > 0.0004f && f2 < 0.065f) atomicAdd(&cnt[2], 1);
  __syncthreads();
  if (t == 0) {
    int m;
    if      (cnt[1] >= 240) m = 1;
    else if (cnt[2] >= 240) m = 2;
    else                    m = 0;
    mode_out[0] = m;
  }
}

// ---------------------------------------------------------------------------
// BIG-PATH pre-pass 1: x f32 -> fp16, NATURAL order (exact).
// ---------------------------------------------------------------------------
__global__ __launch_bounds__(256) void convert_x_nat_kernel(
    const float* __restrict__ xf, u16* __restrict__ xh,
    const int* __restrict__ modep) {
  if (modep && modep[0] != 0) return;
  const int total8 = M_DIM * (K_DIM / 8);
  int idx = blockIdx.x * 256 + threadIdx.x;
  const int stride = gridDim.x * 256;
  for (; idx < total8; idx += stride) {
    const float4* p = (const float4*)(xf + (size_t)idx * 8);
    float4 a = p[0], b = p[1];
    union { _Float16 h[8]; s16x8 v; } r;
    r.h[0] = (_Float16)a.x; r.h[1] = (_Float16)a.y;
    r.h[2] = (_Float16)a.z; r.h[3] = (_Float16)a.w;
    r.h[4] = (_Float16)b.x; r.h[5] = (_Float16)b.y;
    r.h[6] = (_Float16)b.z; r.h[7] = (_Float16)b.w;
    *(s16x8*)(xh + (size_t)idx * 8) = r.v;
  }
}

// ---------------------------------------------------------------------------
// BIG-PATH pre-pass 2: full dequant W -> fp16 [N][K], natural order.
// ---------------------------------------------------------------------------
__global__ __launch_bounds__(256) void dequant_w_kernel(
    const int* __restrict__ packed, const float* __restrict__ scf,
    u16* __restrict__ wf, const int* __restrict__ modep) {
  if (modep && modep[0] != 0) return;
  const int total = N_DIM * (K_DIM / 8);    // 5,636,096 chunks
  int idx = blockIdx.x * 256 + threadIdx.x;
  const int stride = gridDim.x * 256;
  for (; idx < total; idx += stride) {
    const int col = idx >> 9;               // K/8 = 512 chunks per row
    const int d   = idx & 511;
    const float s = scf[col * GROUPS + (d >> 4)];
    const int4 p  = ((const int4*)packed)[idx];
    const int vals[4] = {p.x, p.y, p.z, p.w};
    union { _Float16 h[8]; s16x8 v; } r;
    #pragma unroll
    for (int e = 0; e < 4; ++e) {
      int b = vals[e] & 255;
      r.h[2 * e]     = (_Float16)((float)((b & 15) - 8) * s);
      r.h[2 * e + 1] = (_Float16)((float)(((b >> 4) & 15) - 8) * s);
    }
    *(s16x8*)(wf + (size_t)idx * 8) = r.v;
  }
}

// ---------------------------------------------------------------------------
// BIG-PATH GEMM (R13): pure fp16, BM=128, BN=256; 4 waves 1x4 in n, acc 8x4.
// 2 K-tiles per barrier-phase: 4 LDS bufs (tile%4), 32 phases total.
//  - phase P computes tiles 2P,2P+1 (bufs (P&1)*2,+1), stages tiles
//    2P+2,2P+3 (1<=P<=30) into the bufs read at P-1 (barrier-safe), and
//    prefetches their B fragments.
//  - entry wait vmcnt(16): phase P-1 issued 8 stage loads PINNED (by
//    sched_barrier) before its 16 B loads; <=16 outstanding => stages landed,
//    regardless of any other compiler reordering.
//  - C stored with nontemporal hints: write-once stream must not evict
//    x/W from L2/L3 (R12: FETCH 1.55GB vs 160MB unique input).
// ---------------------------------------------------------------------------
__global__ __launch_bounds__(256, 2) void q4gemm_big_kernel(
    const u16* __restrict__ xh,      // fp16 natural
    const u16* __restrict__ wf,      // fp16 W [N][K]
    float* __restrict__ out,
    const int* __restrict__ modep)
{
  if (modep && modep[0] != 0) return;

  __shared__ _Float16 As[4][128 * 64];   // 64 KiB

  const int tid  = threadIdx.x;
  const int lane = tid & 63;
  const int wv   = tid >> 6;             // 0..3
  const int wn   = wv * 64;
  const int ln15 = lane & 15;
  const int lk   = lane >> 4;            // 0..3

  // XCD swizzle: 2752 = 8 * 344; bm-fastest -> same-XCD neighbors share the
  // 2MB fp16 B panel in L2.
  int bid = blockIdx.x;
  int f   = (bid & 7) * 344 + (bid >> 3);
  int bn  = f / 64;
  int bm  = f - bn * 64;
  const int m0 = bm * 128;
  const int n0 = bn * 256;

  // A staging: LDS[row][slot] = G[row][slot ^ (row&7)] (16B chunks)
  const u16* abase[4];
  #pragma unroll
  for (int q = 0; q < 4; ++q) {
    int row = q * 32 + wv * 8 + (lane >> 3);
    abase[q] = xh + (size_t)(m0 + row) * K_DIM + (((lane & 7) ^ (lane >> 3)) * 8);
  }

#define STAGE(PB, T) do { \
    _Float16* dst = &As[(PB)][0]; \
    _Pragma("unroll") \
    for (int q = 0; q < 4; ++q) \
      __builtin_amdgcn_global_load_lds( \
          (const __attribute__((address_space(1))) void*)(abase[q] + (T) * 64), \
          (__attribute__((address_space(3))) void*)(dst + q * 2048 + wv * 512), \
          16, 0, 0); \
  } while (0)

  // B fragment pointers: col's row contiguous in k.
  const u16* pB[4];
  #pragma unroll
  for (int j = 0; j < 4; ++j) {
    int col = n0 + wn + j * 16 + ln15;
    pB[j] = wf + (size_t)col * K_DIM + lk * 8;
  }

#define LOADB(RB, T) do { \
    _Pragma("unroll") \
    for (int j = 0; j < 4; ++j) { \
      RB[j]     = *(const f16x8*)(pB[j] + (T) * 64); \
      RB[j + 4] = *(const f16x8*)(pB[j] + (T) * 64 + 32); \
    } \
  } while (0)

#define COMPUTE(RB, PB) do { \
    const _Float16* asb = &As[(PB)][0]; \
    _Pragma("unroll") \
    for (int kkc = 0; kkc < 2; ++kkc) { \
      _Pragma("unroll") \
      for (int i = 0; i < 8; ++i) { \
        const int row  = i * 16 + ln15; \
        const int slot = (kkc * 4 + lk) ^ (ln15 & 7); \
        f16x8 af = *(const f16x8*)&asb[row * 64 + slot * 8]; \
        acc[i][0] = __builtin_amdgcn_mfma_f32_16x16x32_f16(af, RB[kkc * 4 + 0], acc[i][0], 0, 0, 0); \
        acc[i][1] = __builtin_amdgcn_mfma_f32_16x16x32_f16(af, RB[kkc * 4 + 1], acc[i][1], 0, 0, 0); \
        acc[i][2] = __builtin_amdgcn_mfma_f32_16x16x32_f16(af, RB[kkc * 4 + 2], acc[i][2], 0, 0, 0); \
        acc[i][3] = __builtin_amdgcn_mfma_f32_16x16x32_f16(af, RB[kkc * 4 + 3], acc[i][3], 0, 0, 0); \
      } \
    } \
  } while (0)

  f32x4 acc[8][4];
  #pragma unroll
  for (int i = 0; i < 8; ++i)
    #pragma unroll
    for (int j = 0; j < 4; ++j)
      acc[i][j] = f32x4{0.f, 0.f, 0.f, 0.f};

  f16x8 rbE[8], rbO[8];

  // prologue: stage tiles 0..3 (bufs 0..3); B(0),B(1); full drain once.
  STAGE(0, 0);
  STAGE(1, 1);
  STAGE(2, 2);
  STAGE(3, 3);
  LOADB(rbE, 0);
  LOADB(rbO, 1);
  asm volatile("s_waitcnt vmcnt(0)" ::: "memory");
  __builtin_amdgcn_s_barrier();

  #pragma unroll 1
  for (int P = 0; P < 32; ++P) {
    const int b0 = (P & 1) * 2;          // buf for tile 2P
    const int s0 = b0 ^ 2;               // stage target pair (read at P-1)

    if (P > 0) {
      asm volatile("s_waitcnt vmcnt(16)" ::: "memory");
      __builtin_amdgcn_s_barrier();
      __builtin_amdgcn_sched_barrier(0);
      if (P <= 30) {
        STAGE(s0, 2 * P + 2);
        STAGE(s0 + 1, 2 * P + 3);
      }
      __builtin_amdgcn_sched_barrier(0);   // pin stages before the 16 B loads
    }

    const int tE = (2 * P + 2 > 63) ? 63 : (2 * P + 2);
    const int tO = (2 * P + 3 > 63) ? 63 : (2 * P + 3);

    __builtin_amdgcn_s_setprio(1);
    COMPUTE(rbE, b0);
    __builtin_amdgcn_s_setprio(0);
    LOADB(rbE, tE);

    __builtin_amdgcn_s_setprio(1);
    COMPUTE(rbO, b0 + 1);
    __builtin_amdgcn_s_setprio(0);
    LOADB(rbO, tO);
  }

  // epilogue: C/D col=lane&15, row=(lane>>4)*4+reg — nontemporal stores.
  #pragma unroll
  for (int i = 0; i < 8; ++i) {
    int r0 = m0 + i * 16 + (lane >> 4) * 4;
    #pragma unroll
    for (int j = 0; j < 4; ++j) {
      int cc = n0 + wn + j * 16 + ln15;
      #pragma unroll
      for (int r = 0; r < 4; ++r)
        __builtin_nontemporal_store(acc[i][j][r], &out[(size_t)(r0 + r) * N_DIM + cc]);
    }
  }
#undef STAGE
#undef LOADB
#undef COMPUTE
}

// ---------------------------------------------------------------------------
// MID PATH (R10 verified, used when ws fits 90MB but not 157MB).
// ---------------------------------------------------------------------------
__global__ __launch_bounds__(256) void convert_x_perm_kernel(
    const float* __restrict__ xf, u16* __restrict__ xh,
    const int* __restrict__ modep) {
  if (modep && modep[0] != 0) return;
  const int total8 = M_DIM * (K_DIM / 8);
  int idx = blockIdx.x * 256 + threadIdx.x;
  const int stride = gridDim.x * 256;
  for (; idx < total8; idx += stride) {
    const float4* p = (const float4*)(xf + (size_t)idx * 8);
    float4 a = p[0], b = p[1];
    union { _Float16 h[8]; s16x8 v; } r;
    r.h[0] = (_Float16)a.x; r.h[1] = (_Float16)b.x;
    r.h[2] = (_Float16)a.y; r.h[3] = (_Float16)b.y;
    r.h[4] = (_Float16)a.z; r.h[5] = (_Float16)b.z;
    r.h[6] = (_Float16)a.w; r.h[7] = (_Float16)b.w;
    *(s16x8*)(xh + (size_t)idx * 8) = r.v;
  }
}

__global__ __launch_bounds__(256) void repack_w_kernel(
    const int* __restrict__ packed, u32* __restrict__ wq) {
  const int total = N_DIM * WQROW;
  int idx = blockIdx.x * 256 + threadIdx.x;
  const int stride = gridDim.x * 256;
  for (; idx < total; idx += stride) {
    const int4 p = ((const int4*)packed)[idx];
    wq[idx] = (u32)(p.x & 255) | ((u32)(p.y & 255) << 8) |
              ((u32)(p.z & 255) << 16) | ((u32)p.w << 24);
  }
}

__device__ __forceinline__ f16x8 dq8(u32 q, h2 s2) {
  const u32 M = 0x000F000Fu, G = 0x64006400u;
  const h2 bias = {(_Float16)(-1032.0f), (_Float16)(-1032.0f)};
  union { u32 u; h2 h; } a0, a1, a2, a3;
  a0.u = (q & M) | G;
  a1.u = ((q >> 4) & M) | G;
  a2.u = ((q >> 8) & M) | G;
  a3.u = ((q >> 12) & M) | G;
  a0.h = (a0.h + bias) * s2;
  a1.h = (a1.h + bias) * s2;
  a2.h = (a2.h + bias) * s2;
  a3.h = (a3.h + bias) * s2;
  union { u32 u[4]; f16x8 f; } r;
  r.u[0] = a0.u; r.u[1] = a1.u; r.u[2] = a2.u; r.u[3] = a3.u;
  return r.f;
}

__global__ __launch_bounds__(256, 2) void q4gemm_mid_kernel(
    const u16* __restrict__ xh, const u32* __restrict__ wq,
    const float* __restrict__ scf, float* __restrict__ out,
    const int* __restrict__ modep)
{
  if (modep && modep[0] != 0) return;

  __shared__ _Float16 As[3][128 * 64];

  const int tid  = threadIdx.x;
  const int lane = tid & 63;
  const int wv   = tid >> 6;
  const int wn   = wv * 64;
  const int ln15 = lane & 15;
  const int lk   = lane >> 4;

  int bid = blockIdx.x;
  int f   = (bid & 7) * 344 + (bid >> 3);
  int bn  = f / 64;
  int bm  = f - bn * 64;
  const int m0 = bm * 128;
  const int n0 = bn * 256;

  const u16* abase[4];
  #pragma unroll
  for (int q = 0; q < 4; ++q) {
    int row = q * 32 + wv * 8 + (lane >> 3);
    abase[q] = xh + (size_t)(m0 + row) * K_DIM + (((lane & 7) ^ (lane >> 3)) * 8);
  }

#define STAGE(PB, T) do { \
    _Float16* dst = &As[(PB)][0]; \
    _Pragma("unroll") \
    for (int q = 0; q < 4; ++q) \
      __builtin_amdgcn_global_load_lds( \
          (const __attribute__((address_space(1))) void*)(abase[q] + (T) * 64), \
          (__attribute__((address_space(3))) void*)(dst + q * 2048 + wv * 512), \
          16, 0, 0); \
  } while (0)

#define LOADB(RB, T) do { \
    _Pragma("unroll") \
    for (int j = 0; j < 4; ++j) { \
      RB[j]     = wq[pcol[j] + (T) * 8]; \
      RB[j + 4] = wq[pcol[j] + (T) * 8 + 4]; \
    } \
  } while (0)

#define COMPUTE(RB, PB) do { \
    const _Float16* asb = &As[(PB)][0]; \
    _Pragma("unroll") \
    for (int kkc = 0; kkc < 2; ++kkc) { \
      f16x8 bfr0 = dq8(RB[kkc * 4 + 0], s2[0]); \
      f16x8 bfr1 = dq8(RB[kkc * 4 + 1], s2[1]); \
      f16x8 bfr2 = dq8(RB[kkc * 4 + 2], s2[2]); \
      f16x8 bfr3 = dq8(RB[kkc * 4 + 3], s2[3]); \
      _Pragma("unroll") \
      for (int i = 0; i < 8; ++i) { \
        const int row  = i * 16 + ln15; \
        const int slot = (kkc * 4 + lk) ^ (ln15 & 7); \
        f16x8 af = *(const f16x8*)&asb[row * 64 + slot * 8]; \
        acc[i][0] = __builtin_amdgcn_mfma_f32_16x16x32_f16(af, bfr0, acc[i][0], 0, 0, 0); \
        acc[i][1] = __builtin_amdgcn_mfma_f32_16x16x32_f16(af, bfr1, acc[i][1], 0, 0, 0); \
        acc[i][2] = __builtin_amdgcn_mfma_f32_16x16x32_f16(af, bfr2, acc[i][2], 0, 0, 0); \
        acc[i][3] = __builtin_amdgcn_mfma_f32_16x16x32_f16(af, bfr3, acc[i][3], 0, 0, 0); \
      } \
    } \
  } while (0)

  int pcol[4], scol[4];
  #pragma unroll
  for (int j = 0; j < 4; ++j) {
    int col = n0 + wn + j * 16 + ln15;
    pcol[j] = col * WQROW + lk;
    scol[j] = col * GROUPS;
  }

  f32x4 acc[8][4];
  #pragma unroll
  for (int i = 0; i < 8; ++i)
    #pragma unroll
    for (int j = 0; j < 4; ++j)
      acc[i][j] = f32x4{0.f, 0.f, 0.f, 0.f};

  u32 rbE[8], rbO[8];
  float snextf[4];
  h2 s2[4];

  STAGE(0, 0);
  STAGE(1, 1);
  LOADB(rbE, 0);
  LOADB(rbO, 1);
  #pragma unroll
  for (int j = 0; j < 4; ++j) snextf[j] = scf[scol[j]];
  asm volatile("s_waitcnt vmcnt(0)" ::: "memory");

  int p0 = 0, p1 = 1, p2 = 2;

  for (int tp = 0; tp < 32; ++tp) {
    const int t0 = 2 * tp;
    const int t1 = t0 + 1;

    asm volatile("s_waitcnt vmcnt(12)" ::: "memory");
    __builtin_amdgcn_s_barrier();
    __builtin_amdgcn_sched_barrier(0);

    #pragma unroll
    for (int j = 0; j < 4; ++j) {
      _Float16 sh = (_Float16)snextf[j];
      s2[j] = h2{sh, sh};
    }
    if (t0 + 2 < 64) STAGE(p2, t0 + 2);

    __builtin_amdgcn_s_setprio(1);
    COMPUTE(rbE, p0);
    __builtin_amdgcn_s_setprio(0);

    if (t0 + 2 < 64) LOADB(rbE, t0 + 2);
    {
      const int gn = (tp + 1 > 31) ? 31 : (tp + 1);
      #pragma unroll
      for (int j = 0; j < 4; ++j) snextf[j] = scf[scol[j] + gn];
    }

    if (tp == 31) {
      asm volatile("s_waitcnt vmcnt(0)" ::: "memory");
    } else {
      asm volatile("s_waitcnt vmcnt(12)" ::: "memory");
    }
    __builtin_amdgcn_s_barrier();
    __builtin_amdgcn_sched_barrier(0);

    if (t1 + 2 < 64) STAGE(p0, t1 + 2);

    __builtin_amdgcn_s_setprio(1);
    COMPUTE(rbO, p1);
    __builtin_amdgcn_s_setprio(0);

    if (t1 + 2 < 64) LOADB(rbO, t1 + 2);

    int tmp = p2; p2 = p1; p1 = p0; p0 = tmp;
  }

  #pragma unroll
  for (int i = 0; i < 8; ++i) {
    int r0 = m0 + i * 16 + (lane >> 4) * 4;
    #pragma unroll
    for (int j = 0; j < 4; ++j) {
      int cc = n0 + wn + j * 16 + ln15;
      #pragma unroll
      for (int r = 0; r < 4; ++r)
        out[(size_t)(r0 + r) * N_DIM + cc] = acc[i][j][r];
    }
  }
#undef STAGE
#undef LOADB
#undef COMPUTE
}

// ---------------------------------------------------------------------------
// SLOW FALLBACK (any mode; skips mode 0 when a fast path ran).
// ---------------------------------------------------------------------------
__global__ __launch_bounds__(256) void q4gemm_slow_kernel(
    const void* __restrict__ xraw,
    const int*  __restrict__ packed,
    const void* __restrict__ scraw,
    float* __restrict__ out,
    const int* __restrict__ modep,
    int skip0)
{
  const int mode = modep ? modep[0] : 0;
  if (skip0 && mode == 0) return;

  __shared__ u16 Asl[128 * LDSK];
  __shared__ u16 Bsl[128 * LDSK];

  const int tid  = threadIdx.x;
  const int lane = tid & 63;
  const int wv   = tid >> 6;
  const int wm   = (wv >> 1) * 64;
  const int wn   = (wv & 1) * 64;
  const int n0   = blockIdx.x * 128;
  const int m0   = blockIdx.y * 128;

  f32x4 acc[4][4];
  #pragma unroll
  for (int i = 0; i < 4; ++i)
    #pragma unroll
    for (int j = 0; j < 4; ++j)
      acc[i][j] = f32x4{0.f, 0.f, 0.f, 0.f};

  const int lrow16 = lane & 15;
  const int lk8    = (lane >> 4) * 8;

  for (int k0 = 0; k0 < K_DIM; k0 += 64) {
    if (mode == 0) {
      const float* xf = (const float*)xraw;
      #pragma unroll
      for (int it = 0; it < 4; ++it) {
        int s = tid + it * 256;
        int row = s >> 3, c8 = (s & 7) * 8;
        const float4* p = (const float4*)(xf + (size_t)(m0 + row) * K_DIM + k0 + c8);
        float4 v0 = p[0], v1 = p[1];
        u16 tmp[8] = { f2bf(v0.x), f2bf(v0.y), f2bf(v0.z), f2bf(v0.w),
                       f2bf(v1.x), f2bf(v1.y), f2bf(v1.z), f2bf(v1.w) };
        *(s16x8*)&Asl[row * LDSK + c8] = *(const s16x8*)tmp;
      }
    } else if (mode == 1) {
      const u16* xhh = (const u16*)xraw;
      #pragma unroll
      for (int it = 0; it < 4; ++it) {
        int s = tid + it * 256;
        int row = s >> 3, c8 = (s & 7) * 8;
        s16x8 v = *(const s16x8*)(xhh + (size_t)(m0 + row) * K_DIM + k0 + c8);
        u16 tmp[8];
        #pragma unroll
        for (int j = 0; j < 8; ++j) tmp[j] = f2bf(h2f((u16)v[j]));
        *(s16x8*)&Asl[row * LDSK + c8] = *(const s16x8*)tmp;
      }
    } else {
      const u16* xhh = (const u16*)xraw;
      #pragma unroll
      for (int it = 0; it < 4; ++it) {
        int s = tid + it * 256;
        int row = s >> 3, c8 = (s & 7) * 8;
        s16x8 v = *(const s16x8*)(xhh + (size_t)(m0 + row) * K_DIM + k0 + c8);
        *(s16x8*)&Asl[row * LDSK + c8] = v;
      }
    }

    {
      int row  = tid >> 1;
      int half = tid & 1;
      int srw  = n0 + row;
      int g    = k0 >> 7;
      float scale;
      if      (mode == 0) scale = ((const float*)scraw)[(size_t)srw * GROUPS + g];
      else if (mode == 1) scale = h2f(((const u16*)scraw)[(size_t)srw * GROUPS + g]);
      else                scale = bf2f(((const u16*)scraw)[(size_t)srw * GROUPS + g]);

      const int4* pp = (const int4*)(packed + (size_t)srw * (K_DIM / 2) + (k0 >> 1) + half * 16);
      #pragma unroll
      for (int j = 0; j < 4; ++j) {
        int4 pv = pp[j];
        int vals[4] = {pv.x, pv.y, pv.z, pv.w};
        u16 w[8];
        #pragma unroll
        for (int e = 0; e < 4; ++e) {
          int b = vals[e] & 255;
          w[e * 2]     = f2bf(scale * (float)((b & 15) - 8));
          w[e * 2 + 1] = f2bf(scale * (float)(((b >> 4) & 15) - 8));
        }
        int i0 = half * 16 + j * 4;
        *(s16x8*)&Bsl[row * LDSK + i0 * 2] = *(const s16x8*)w;
      }
    }
    __syncthreads();

    #pragma unroll
    for (int kk = 0; kk < 64; kk += 32) {
      s16x8 af[4], bfr[4];
      int klane = kk + lk8;
      #pragma unroll
      for (int i = 0; i < 4; ++i)
        af[i] = *(const s16x8*)&Asl[(wm + i * 16 + lrow16) * LDSK + klane];
      #pragma unroll
      for (int i = 0; i < 4; ++i)
        bfr[i] = *(const s16x8*)&Bsl[(wn + i * 16 + lrow16) * LDSK + klane];
      #pragma unroll
      for (int i = 0; i < 4; ++i)
        #pragma unroll
        for (int j = 0; j < 4; ++j)
          acc[i][j] = __builtin_amdgcn_mfma_f32_16x16x32_bf16(af[i], bfr[j], acc[i][j], 0, 0, 0);
    }
    __syncthreads();
  }

  #pragma unroll
  for (int i = 0; i < 4; ++i) {
    int rbase = m0 + wm + i * 16 + ((lane >> 4) * 4);
    #pragma unroll
    for (int j = 0; j < 4; ++j) {
      int c = n0 + wn + j * 16 + (lane & 15);
      #pragma unroll
      for (int r = 0; r < 4; ++r)
        out[(size_t)(rbase + r) * N_DIM + c] = acc[i][j][r];
    }
  }
}

extern "C" void kernel_launch(void* const* d_in, const int* in_sizes, int n_in,
                              void* d_out, int out_size, void* d_ws, size_t ws_size,
                              hipStream_t stream) {
  const void* x      = d_in[0];
  const int*  packed = (const int*)d_in[1];
  const void* scales = d_in[2];
  float* out = (float*)d_out;

  const size_t XB = (size_t)M_DIM * K_DIM * 2;        // 67,108,864 B
  const size_t WF = (size_t)N_DIM * K_DIM * 2;        // 90,177,536 B
  const size_t WQ = (size_t)N_DIM * WQROW * 4;        // 22,544,384 B
  const size_t NEED_BIG = 256 + XB + WF;              // ~157.3 MB
  const size_t NEED_MID = 256 + XB + WQ;              // ~89.7 MB

  int* mode_flag = nullptr;
  if (ws_size >= 4) {
    mode_flag = (int*)d_ws;
    probe_mode_kernel<<<dim3(1), dim3(256), 0, stream>>>(scales, mode_flag);
  }

  int fast = 0;
  if (mode_flag && ws_size >= NEED_BIG) fast = 2;
  else if (mode_flag && ws_size >= NEED_MID) fast = 1;

  if (fast == 2) {
    u16* xh = (u16*)((char*)d_ws + 256);
    u16* wf = (u16*)((char*)d_ws + 256 + XB);
    convert_x_nat_kernel<<<dim3(2048), dim3(256), 0, stream>>>(
        (const float*)x, xh, mode_flag);
    dequant_w_kernel<<<dim3(2048), dim3(256), 0, stream>>>(
        packed, (const float*)scales, wf, mode_flag);
    q4gemm_big_kernel<<<dim3(2752), dim3(256), 0, stream>>>(
        xh, wf, out, mode_flag);
  } else if (fast == 1) {
    u16* xh = (u16*)((char*)d_ws + 256);
    u32* wq = (u32*)((char*)d_ws + 256 + XB);
    convert_x_perm_kernel<<<dim3(2048), dim3(256), 0, stream>>>(
        (const float*)x, xh, mode_flag);
    repack_w_kernel<<<dim3(2048), dim3(256), 0, stream>>>(packed, wq);
    q4gemm_mid_kernel<<<dim3(2752), dim3(256), 0, stream>>>(
        xh, wq, (const float*)scales, out, mode_flag);
  }

  q4gemm_slow_kernel<<<dim3(N_DIM / 128, M_DIM / 128), dim3(256), 0, stream>>>(
      x, packed, scales, out, mode_flag, fast);
}